// Round 4
// baseline (2113.296 us; speedup 1.0000x reference)
//
#include <hip/hip_runtime.h>

#define DIMS 3
#define NB 256
#define NN 256
#define KK 16
#define HID 64
#define EPG 8192
#define NTOT (NB*NN)
#define NE (NB*EPG)

// d_out layout (flat concat of reference outputs, all as float)
#define PX_OFF   0          // (B*K, F, DIMS)           = 786432
#define PEI_OFF  786432     // (2, B*K*K)               = 131072
#define PEA_OFF  917504     // (B*K*K, DIMS)            = 196608
#define PB_OFF   1114112    // (B*K,)                   = 4096
#define LOSS_OFF 1118208    // scalar
#define S_OFF    1118209    // (DIMS, B, N, K)          = 3145728

// d_ws layout (bytes) — total ~27.5 MB
#define WREC_WS  0                 // float[3][NB*EPG] per-d edge weight (CSR order) = 24 MB
#define CLREC_WS 25165824          // uchar[NB*EPG] col-local index
#define IPTR_WS  27262976          // int[NB*257]
#define ENT_WS   27526144          // float[768]
#define MOD_WS   27529216          // float[768]
#define WC_WS    27532288          // float[144*16]  (fcW1 @ fcW2)
#define BC_WS    27541504          // float[16]      (fcb1 @ fcW2 + fcb2)

// ---------------- combined FC weights: Wc = fcW1@fcW2, bc = fcb1@fcW2+fcb2 ----------------
__global__ void fc_combine(const float* __restrict__ fcW1, const float* __restrict__ fcb1,
                           const float* __restrict__ fcW2, const float* __restrict__ fcb2,
                           float* __restrict__ wc, float* __restrict__ bc)
{
    const int t = threadIdx.x;
    for (int idx = t; idx < 144 * 16; idx += 256) {
        const int i = idx >> 4, k = idx & 15;
        float s = 0.f;
        for (int q = 0; q < 50; ++q) s += fcW1[i * 50 + q] * fcW2[q * 16 + k];
        wc[idx] = s;
    }
    if (t < 16) {
        float s = fcb2[t];
        for (int q = 0; q < 50; ++q) s += fcb1[q] * fcW2[q * 16 + t];
        bc[t] = s;
    }
}

// ---------------- CSR build (deterministic stable counting sort) ----------------
__launch_bounds__(256)
__global__ void csr_build(const int* __restrict__ edge_index,
                          const float* __restrict__ edge_attr,
                          float* __restrict__ wrec, unsigned char* __restrict__ clrec,
                          int* __restrict__ indptr)
{
    __shared__ int rl[EPG];              // 32 KB
    __shared__ unsigned char clb[EPG];   // 8 KB
    __shared__ int cnt[256];
    __shared__ int sc[256];
    const int b = blockIdx.x;
    const int t = threadIdx.x;
    const int* rowp = edge_index + (size_t)b * EPG;
    const int* colp = edge_index + (size_t)NB * EPG + (size_t)b * EPG;
    for (int i = t; i < EPG; i += 256) {
        rl[i] = rowp[i] & (NN - 1);
        clb[i] = (unsigned char)(colp[i] & (NN - 1));
    }
    cnt[t] = 0;
    __syncthreads();
    for (int i = t; i < EPG; i += 256) atomicAdd(&cnt[rl[i]], 1);
    __syncthreads();
    sc[t] = cnt[t];
    __syncthreads();
    for (int ofs = 1; ofs < 256; ofs <<= 1) {
        int v = (t >= ofs) ? sc[t - ofs] : 0;
        __syncthreads();
        sc[t] += v;
        __syncthreads();
    }
    const int start = sc[t] - cnt[t];
    indptr[b * 257 + t] = start;
    if (t == 255) indptr[b * 257 + 256] = EPG;
    // stable claim: scan edges in order; thread t takes its row's edges
    const float* eap = edge_attr + (size_t)b * EPG * 3;
    float* w0 = wrec + (size_t)b * EPG;
    float* w1 = wrec + (size_t)NB * EPG + (size_t)b * EPG;
    float* w2 = wrec + 2 * (size_t)NB * EPG + (size_t)b * EPG;
    unsigned char* cdst = clrec + (size_t)b * EPG;
    int c = start;
    for (int e4 = 0; e4 < EPG; e4 += 4) {
        const int4 r4 = *(const int4*)&rl[e4];
        const int rv[4] = {r4.x, r4.y, r4.z, r4.w};
        #pragma unroll
        for (int u = 0; u < 4; ++u) {
            if (rv[u] == t) {
                const int e = e4 + u;
                w0[c] = eap[e * 3 + 0];
                w1[c] = eap[e * 3 + 1];
                w2[c] = eap[e * 3 + 2];
                cdst[c] = clb[e];
                ++c;
            }
        }
    }
}

// ---------------- gconv: 3 layers + combined FC + softmax fused, per (d,b) block ----------------
template<int OUTW, bool WRITE_H>
__device__ __forceinline__ void layer_step(
    int t, int r, int half, int js, int je,
    const float* __restrict__ wp, const unsigned char* __restrict__ clp,
    const float* __restrict__ Wm, const float* __restrict__ Ws,
    const float* __restrict__ bias, const float* __restrict__ wc, // wc + layer_row_off*16
    float4* hb4, float4* ab4, float* t16)
{
    constexpr int NCOL = OUTW / 2;
    __syncthreads();                       // [A] hb stable
    // gather agg[r][half*32 .. +32) from CSR, register-accumulated
    float ga[32];
    #pragma unroll
    for (int u = 0; u < 32; ++u) ga[u] = 0.f;
    const int cb = half * 8;
    for (int j = js; j < je; ++j) {
        const int cl = clp[j];
        const float w = wp[j];
        const int base = cl * 16, sw = cl & 15;
        #pragma unroll
        for (int u = 0; u < 8; ++u) {
            const float4 h4 = hb4[base + ((cb + u) ^ sw)];
            ga[u*4+0] += w * h4.x; ga[u*4+1] += w * h4.y;
            ga[u*4+2] += w * h4.z; ga[u*4+3] += w * h4.w;
        }
    }
    {
        const int base = r * 16, sw = r & 15;
        #pragma unroll
        for (int u = 0; u < 8; ++u) {
            float4 v; v.x = ga[u*4+0]; v.y = ga[u*4+1]; v.z = ga[u*4+2]; v.w = ga[u*4+3];
            ab4[base + ((cb + u) ^ sw)] = v;
        }
    }
    __syncthreads();                       // [B]
    // dense: h_next[r][j0..j0+NCOL) = relu(agg@Wm + h@Ws + b)
    const int j0 = half * NCOL;
    float acc[NCOL];
    #pragma unroll
    for (int jj = 0; jj < NCOL; ++jj) acc[jj] = bias[j0 + jj];
    const int rbase = r * 16, rsw = r & 15;
    for (int ic = 0; ic < 16; ++ic) {
        const float4 a4 = ab4[rbase + (ic ^ rsw)];
        const float4 h4 = hb4[rbase + (ic ^ rsw)];
        const float av[4] = {a4.x, a4.y, a4.z, a4.w};
        const float hv[4] = {h4.x, h4.y, h4.z, h4.w};
        #pragma unroll
        for (int u = 0; u < 4; ++u) {
            const int i = ic * 4 + u;
            const float a = av[u], h = hv[u];
            const float* wmr = Wm + i * OUTW + j0;
            const float* wsr = Ws + i * OUTW + j0;
            #pragma unroll
            for (int q4 = 0; q4 < NCOL / 4; ++q4) {
                const float4 wm4 = *(const float4*)(wmr + q4 * 4);
                const float4 ws4 = *(const float4*)(wsr + q4 * 4);
                acc[q4*4+0] += a * wm4.x + h * ws4.x;
                acc[q4*4+1] += a * wm4.y + h * ws4.y;
                acc[q4*4+2] += a * wm4.z + h * ws4.z;
                acc[q4*4+3] += a * wm4.w + h * ws4.w;
            }
        }
    }
    #pragma unroll
    for (int jj = 0; jj < NCOL; ++jj) acc[jj] = fmaxf(acc[jj], 0.f);
    __syncthreads();                       // [C] all hb/ab reads done
    if (WRITE_H) {
        const int base = r * 16, sw = r & 15;
        #pragma unroll
        for (int u = 0; u < NCOL / 4; ++u) {
            float4 v; v.x = acc[u*4+0]; v.y = acc[u*4+1]; v.z = acc[u*4+2]; v.w = acc[u*4+3];
            hb4[base + ((cb + u) ^ sw)] = v;
        }
    }
    // t16 += h_next @ Wc[layer rows]  (16-wide combined FC)
    #pragma unroll
    for (int jj = 0; jj < NCOL; ++jj) {
        const float hvv = acc[jj];
        const float* wr = wc + (j0 + jj) * 16;
        #pragma unroll
        for (int q4 = 0; q4 < 4; ++q4) {
            const float4 w4 = *(const float4*)(wr + q4 * 4);
            t16[q4*4+0] += hvv * w4.x;
            t16[q4*4+1] += hvv * w4.y;
            t16[q4*4+2] += hvv * w4.z;
            t16[q4*4+3] += hvv * w4.w;
        }
    }
}

__launch_bounds__(512, 2)   // LDS caps us at 1 block/CU (2 waves/EU) — let regalloc use 256 VGPRs
__global__ void gconv_kernel(
    const float* __restrict__ x,
    const float* __restrict__ Wm0, const float* __restrict__ Ws0, const float* __restrict__ b0,
    const float* __restrict__ Wm1, const float* __restrict__ Ws1, const float* __restrict__ b1,
    const float* __restrict__ Wm2, const float* __restrict__ Ws2, const float* __restrict__ b2,
    const float* __restrict__ wcomb, const float* __restrict__ bcomb,
    const float* __restrict__ wrec, const unsigned char* __restrict__ clrec,
    const int* __restrict__ indptr,
    float* __restrict__ out, float* __restrict__ entpart)
{
    __shared__ float4 hb4[4096];   // h tile, XOR-chunk-swizzled  (64 KB)
    __shared__ float4 ab4[4096];   // agg tile / t16 exchange     (64 KB)
    __shared__ float  red[8];
    float* ab = (float*)ab4;
    const int t = threadIdx.x;
    const int bid = blockIdx.x;
    const int d = bid >> 8;
    const int b = bid & (NB - 1);
    const int r = t & (NN - 1);
    const int half = t >> 8;
    const int lane = t & 63;
    const int wave = t >> 6;

    // stage x -> hb (swizzled)
    {
        const float4* xv = (const float4*)(x + (size_t)b * NN * HID);
        #pragma unroll
        for (int it = 0; it < 8; ++it) {
            const int idx = t + it * 512;
            const int nrow = idx >> 4, c = idx & 15;
            hb4[nrow * 16 + (c ^ (nrow & 15))] = xv[idx];
        }
    }
    float t16[16];
    #pragma unroll
    for (int q = 0; q < 16; ++q) t16[q] = 0.f;

    const float* wp = wrec + (size_t)d * NB * EPG + (size_t)b * EPG;
    const unsigned char* clp = clrec + (size_t)b * EPG;
    const int js = indptr[b * 257 + r];
    const int je = indptr[b * 257 + r + 1];

    layer_step<64, true >(t, r, half, js, je, wp, clp, Wm0 + d*HID*HID, Ws0 + d*HID*HID,
                          b0 + d*HID, wcomb,            hb4, ab4, t16);
    layer_step<64, true >(t, r, half, js, je, wp, clp, Wm1 + d*HID*HID, Ws1 + d*HID*HID,
                          b1 + d*HID, wcomb + 64*16,    hb4, ab4, t16);
    layer_step<16, false>(t, r, half, js, je, wp, clp, Wm2 + d*HID*KK,  Ws2 + d*HID*KK,
                          b2 + d*KK,  wcomb + 128*16,   hb4, ab4, t16);

    // exchange t16 halves via ab (layout [k][r]: 64 lanes hit 64 distinct banks 2-way)
    __syncthreads();
    if (half == 1) {
        #pragma unroll
        for (int k = 0; k < 16; ++k) ab[(k << 8) + r] = t16[k];
    }
    __syncthreads();
    float ent_local = 0.f;
    if (half == 0) {
        float logits[KK];
        #pragma unroll
        for (int k = 0; k < KK; ++k) logits[k] = t16[k] + ab[(k << 8) + r] + bcomb[k];
        float m = logits[0];
        #pragma unroll
        for (int k = 1; k < KK; ++k) m = fmaxf(m, logits[k]);
        float sum = 0.f, sv[KK];
        #pragma unroll
        for (int k = 0; k < KK; ++k) { sv[k] = expf(logits[k] - m); sum += sv[k]; }
        const float inv = 1.f / sum;
        float* sp = out + S_OFF + ((size_t)(d * NB + b) * NN + r) * KK;
        #pragma unroll
        for (int k = 0; k < KK; ++k) {
            const float s = sv[k] * inv;
            sp[k] = s;
            ent_local -= s * logf(s + 1e-15f);
        }
    }
    #pragma unroll
    for (int off = 32; off; off >>= 1) ent_local += __shfl_down(ent_local, off);
    if (lane == 0) red[wave] = ent_local;
    __syncthreads();
    if (t == 0) {
        float s = 0.f;
        #pragma unroll
        for (int w = 0; w < 8; ++w) s += red[w];
        entpart[bid] = s;
    }
}

// ---------------- pool: padj = sum_r s[r] (x) G[r], G = A s ; + mod + px ----------------
#define SSTR 20
__launch_bounds__(256)
__global__ void pool_kernel(
    const float* __restrict__ x_to_pool,
    const float* __restrict__ wrec, const unsigned char* __restrict__ clrec,
    const int* __restrict__ indptr,
    const float* __restrict__ out_s, float* __restrict__ out, float* __restrict__ modpart)
{
    __shared__ float sl[NN * SSTR];       // 20 KB
    __shared__ float gl[NN * SSTR];       // 20 KB
    __shared__ float padjw[4 * 256];      // per-wave partials (deterministic merge)
    __shared__ float red[4];
    const int t = threadIdx.x;
    const int bid = blockIdx.x;
    const int d = bid >> 8;
    const int b = bid & (NB - 1);
    const int lane = t & 63;
    const int wave = t >> 6;

    {
        const float4* sp4 = (const float4*)(out_s + S_OFF + (size_t)(d * NB + b) * NN * KK);
        #pragma unroll
        for (int it = 0; it < 4; ++it) {
            const int idx = t + it * 256;
            const int nrow = idx >> 2, c = idx & 3;
            *(float4*)(sl + nrow * SSTR + c * 4) = sp4[idx];
        }
    }
    __syncthreads();

    const float* wp = wrec + (size_t)d * NB * EPG + (size_t)b * EPG;
    const unsigned char* clp = clrec + (size_t)b * EPG;
    const int js = indptr[b * 257 + t];
    const int je = indptr[b * 257 + t + 1];
    float sr[16];
    {
        #pragma unroll
        for (int c = 0; c < 4; ++c) {
            const float4 v = *(const float4*)(sl + t * SSTR + c * 4);
            sr[c*4+0] = v.x; sr[c*4+1] = v.y; sr[c*4+2] = v.z; sr[c*4+3] = v.w;
        }
    }
    float g[16];
    #pragma unroll
    for (int k = 0; k < 16; ++k) g[k] = 0.f;
    float modacc = 0.f;
    for (int j = js; j < je; ++j) {
        const int cl = clp[j];
        const float w = wp[j];
        const float* srow = sl + cl * SSTR;
        float ss = 0.f;
        #pragma unroll
        for (int c = 0; c < 4; ++c) {
            const float4 sv = *(const float4*)(srow + c * 4);
            g[c*4+0] += w * sv.x; g[c*4+1] += w * sv.y;
            g[c*4+2] += w * sv.z; g[c*4+3] += w * sv.w;
            const float d0 = sr[c*4+0] - sv.x, d1 = sr[c*4+1] - sv.y;
            const float d2 = sr[c*4+2] - sv.z, d3 = sr[c*4+3] - sv.w;
            ss += d0*d0 + d1*d1 + d2*d2 + d3*d3;
        }
        modacc += w * ss;
    }
    {
        #pragma unroll
        for (int c = 0; c < 4; ++c) {
            float4 v; v.x = g[c*4+0]; v.y = g[c*4+1]; v.z = g[c*4+2]; v.w = g[c*4+3];
            *(float4*)(gl + t * SSTR + c * 4) = v;
        }
    }
    __syncthreads();

    // padj[k][l] = sum_r s[r][k] * G[r][l]; wave w covers r in [w*64, w*64+64)
    {
        const int k = t & 15, lg = (t >> 4) & 3;
        float p0 = 0.f, p1 = 0.f, p2 = 0.f, p3 = 0.f;
        const int r0 = wave * 64;
        for (int rr = r0; rr < r0 + 64; ++rr) {
            const float sk = sl[rr * SSTR + k];
            const float4 g4 = *(const float4*)(gl + rr * SSTR + lg * 4);
            p0 += sk * g4.x; p1 += sk * g4.y; p2 += sk * g4.z; p3 += sk * g4.w;
        }
        float* pw = padjw + wave * 256 + k * 16 + lg * 4;
        pw[0] = p0; pw[1] = p1; pw[2] = p2; pw[3] = p3;
    }

    // px[k][f] = sum_n s[n][k] * xtp[n][f*3+d]
    {
        const int f = t & 63;
        const int kg = t >> 6;
        float xa0 = 0.f, xa1 = 0.f, xa2 = 0.f, xa3 = 0.f;
        const float* xp = x_to_pool + (size_t)b * NN * (64 * DIMS) + f * DIMS + d;
        #pragma unroll 4
        for (int nn2 = 0; nn2 < NN; ++nn2) {
            const float xv = xp[(size_t)nn2 * (64 * DIMS)];
            const float4 s4 = *(const float4*)(sl + nn2 * SSTR + kg * 4);
            xa0 += xv * s4.x; xa1 += xv * s4.y; xa2 += xv * s4.z; xa3 += xv * s4.w;
        }
        const float sc = 1.f / 16.f;  // K/N
        out[PX_OFF + ((size_t)((b * KK + kg * 4 + 0) * 64) + f) * DIMS + d] = xa0 * sc;
        out[PX_OFF + ((size_t)((b * KK + kg * 4 + 1) * 64) + f) * DIMS + d] = xa1 * sc;
        out[PX_OFF + ((size_t)((b * KK + kg * 4 + 2) * 64) + f) * DIMS + d] = xa2 * sc;
        out[PX_OFF + ((size_t)((b * KK + kg * 4 + 3) * 64) + f) * DIMS + d] = xa3 * sc;
    }

    #pragma unroll
    for (int off = 32; off; off >>= 1) modacc += __shfl_down(modacc, off);
    if (lane == 0) red[wave] = modacc;
    __syncthreads();   // also fences padjw
    if (t == 0) modpart[bid] = red[0] + red[1] + red[2] + red[3];

    {
        const float v = (padjw[t] + padjw[256 + t] + padjw[512 + t] + padjw[768 + t]) * (1.f / 256.f);
        out[PEA_OFF + (size_t)((b * KK + (t >> 4)) * KK + (t & 15)) * DIMS + d] = v;
    }
}

__global__ void aux_kernel(float* __restrict__ out)
{
    const int idx = blockIdx.x * 256 + threadIdx.x;
    if (idx < 2 * NTOT) {
        const int r = idx & (NTOT - 1);
        const int bb = r >> 8;
        const int j = r & 255;
        const int v = (idx < NTOT) ? (bb * KK + (j >> 4)) : (bb * KK + (j & 15));
        out[PEI_OFF + idx] = (float)v;
    } else if (idx < 2 * NTOT + NB * KK) {
        const int i = idx - 2 * NTOT;
        out[PB_OFF + i] = (float)(i >> 4);
    }
}

__global__ void loss_kernel(const float* __restrict__ entpart,
                            const float* __restrict__ modpart,
                            float* __restrict__ out)
{
    const int tid = threadIdx.x;
    float e = 0.f, m = 0.f;
    for (int i = tid; i < DIMS * NB; i += 256) { e += entpart[i]; m += modpart[i]; }
    #pragma unroll
    for (int off = 32; off; off >>= 1) { e += __shfl_down(e, off); m += __shfl_down(m, off); }
    __shared__ float er[4], mr[4];
    const int wave = tid >> 6, lane = tid & 63;
    if (lane == 0) { er[wave] = e; mr[wave] = m; }
    __syncthreads();
    if (tid == 0) {
        const float es = er[0] + er[1] + er[2] + er[3];
        const float ms = mr[0] + mr[1] + mr[2] + mr[3];
        out[LOSS_OFF] = ms / (float)NE + es / (float)(DIMS * NTOT);
    }
}

extern "C" void kernel_launch(void* const* d_in, const int* in_sizes, int n_in,
                              void* d_out, int out_size, void* d_ws, size_t ws_size,
                              hipStream_t stream)
{
    const float* x         = (const float*)d_in[0];
    const float* edge_attr = (const float*)d_in[1];
    const float* x_to_pool = (const float*)d_in[2];
    const float* Wm0 = (const float*)d_in[3];
    const float* Ws0 = (const float*)d_in[4];
    const float* b0  = (const float*)d_in[5];
    const float* Wm1 = (const float*)d_in[6];
    const float* Ws1 = (const float*)d_in[7];
    const float* b1  = (const float*)d_in[8];
    const float* Wm2 = (const float*)d_in[9];
    const float* Ws2 = (const float*)d_in[10];
    const float* b2  = (const float*)d_in[11];
    const float* fcW1= (const float*)d_in[12];
    const float* fcb1= (const float*)d_in[13];
    const float* fcW2= (const float*)d_in[14];
    const float* fcb2= (const float*)d_in[15];
    const int* edge_index = (const int*)d_in[16];
    float* out = (float*)d_out;
    char* ws = (char*)d_ws;
    float*         wrec  = (float*)(ws + WREC_WS);
    unsigned char* clrec = (unsigned char*)(ws + CLREC_WS);
    int*           iptr  = (int*)(ws + IPTR_WS);
    float*         entpart = (float*)(ws + ENT_WS);
    float*         modpart = (float*)(ws + MOD_WS);
    float*         wc    = (float*)(ws + WC_WS);
    float*         bc    = (float*)(ws + BC_WS);

    csr_build<<<dim3(NB), dim3(256), 0, stream>>>(edge_index, edge_attr, wrec, clrec, iptr);
    fc_combine<<<dim3(1), dim3(256), 0, stream>>>(fcW1, fcb1, fcW2, fcb2, wc, bc);
    gconv_kernel<<<dim3(DIMS * NB), dim3(512), 0, stream>>>(
        x, Wm0, Ws0, b0, Wm1, Ws1, b1, Wm2, Ws2, b2,
        wc, bc, wrec, clrec, iptr, out, entpart);
    pool_kernel<<<dim3(DIMS * NB), dim3(256), 0, stream>>>(
        x_to_pool, wrec, clrec, iptr, out, out, modpart);
    aux_kernel<<<dim3((2 * NTOT + NB * KK + 255) / 256), dim3(256), 0, stream>>>(out);
    loss_kernel<<<dim3(1), dim3(256), 0, stream>>>(entpart, modpart, out);
}

// Round 5
// 2108.946 us; speedup vs baseline: 1.0021x; 1.0021x over previous
//
#include <hip/hip_runtime.h>

#define DIMS 3
#define NB 256
#define NN 256
#define KK 16
#define HID 64
#define EPG 8192
#define NTOT (NB*NN)
#define NE (NB*EPG)

// d_out layout (flat concat of reference outputs, all as float)
#define PX_OFF   0          // (B*K, F, DIMS)           = 786432
#define PEI_OFF  786432     // (2, B*K*K)               = 131072
#define PEA_OFF  917504     // (B*K*K, DIMS)            = 196608
#define PB_OFF   1114112    // (B*K,)                   = 4096
#define LOSS_OFF 1118208    // scalar
#define S_OFF    1118209    // (DIMS, B, N, K)          = 3145728

// d_ws layout (bytes) — total ~27.5 MB
#define WREC_WS  0                 // float[3][NB*EPG] per-d edge weight (CSR order) = 24 MB
#define CLREC_WS 25165824          // uchar[NB*EPG] col-local index
#define IPTR_WS  27262976          // int[NB*257]
#define ENT_WS   27526144          // float[768]
#define MOD_WS   27529216          // float[768]
#define WC_WS    27532288          // float[144*16]  (fcW1 @ fcW2)
#define BC_WS    27541504          // float[16]      (fcb1 @ fcW2 + fcb2)

// ---------------- combined FC weights: Wc = fcW1@fcW2, bc = fcb1@fcW2+fcb2 ----------------
__global__ void fc_combine(const float* __restrict__ fcW1, const float* __restrict__ fcb1,
                           const float* __restrict__ fcW2, const float* __restrict__ fcb2,
                           float* __restrict__ wc, float* __restrict__ bc)
{
    const int t = threadIdx.x;
    for (int idx = t; idx < 144 * 16; idx += 256) {
        const int i = idx >> 4, k = idx & 15;
        float s = 0.f;
        for (int q = 0; q < 50; ++q) s += fcW1[i * 50 + q] * fcW2[q * 16 + k];
        wc[idx] = s;
    }
    if (t < 16) {
        float s = fcb2[t];
        for (int q = 0; q < 50; ++q) s += fcb1[q] * fcW2[q * 16 + t];
        bc[t] = s;
    }
}

// ---------------- CSR build (deterministic stable counting sort) ----------------
__launch_bounds__(256)
__global__ void csr_build(const int* __restrict__ edge_index,
                          const float* __restrict__ edge_attr,
                          float* __restrict__ wrec, unsigned char* __restrict__ clrec,
                          int* __restrict__ indptr)
{
    __shared__ int rl[EPG];              // 32 KB
    __shared__ unsigned char clb[EPG];   // 8 KB
    __shared__ int cnt[256];
    __shared__ int sc[256];
    const int b = blockIdx.x;
    const int t = threadIdx.x;
    const int* rowp = edge_index + (size_t)b * EPG;
    const int* colp = edge_index + (size_t)NB * EPG + (size_t)b * EPG;
    for (int i = t; i < EPG; i += 256) {
        rl[i] = rowp[i] & (NN - 1);
        clb[i] = (unsigned char)(colp[i] & (NN - 1));
    }
    cnt[t] = 0;
    __syncthreads();
    for (int i = t; i < EPG; i += 256) atomicAdd(&cnt[rl[i]], 1);
    __syncthreads();
    sc[t] = cnt[t];
    __syncthreads();
    for (int ofs = 1; ofs < 256; ofs <<= 1) {
        int v = (t >= ofs) ? sc[t - ofs] : 0;
        __syncthreads();
        sc[t] += v;
        __syncthreads();
    }
    const int start = sc[t] - cnt[t];
    indptr[b * 257 + t] = start;
    if (t == 255) indptr[b * 257 + 256] = EPG;
    // stable claim: scan edges in order; thread t takes its row's edges
    const float* eap = edge_attr + (size_t)b * EPG * 3;
    float* w0 = wrec + (size_t)b * EPG;
    float* w1 = wrec + (size_t)NB * EPG + (size_t)b * EPG;
    float* w2 = wrec + 2 * (size_t)NB * EPG + (size_t)b * EPG;
    unsigned char* cdst = clrec + (size_t)b * EPG;
    int c = start;
    for (int e4 = 0; e4 < EPG; e4 += 4) {
        const int4 r4 = *(const int4*)&rl[e4];
        const int rv[4] = {r4.x, r4.y, r4.z, r4.w};
        #pragma unroll
        for (int u = 0; u < 4; ++u) {
            if (rv[u] == t) {
                const int e = e4 + u;
                w0[c] = eap[e * 3 + 0];
                w1[c] = eap[e * 3 + 1];
                w2[c] = eap[e * 3 + 2];
                cdst[c] = clb[e];
                ++c;
            }
        }
    }
}

// ---------------- gconv: 3 layers + combined FC + softmax fused, per (d,b) block ----------------
template<int OUTW, bool WRITE_H>
__device__ __forceinline__ void layer_step(
    int t, int r, int half, int js, int je,
    const float* __restrict__ wp, const unsigned char* __restrict__ clp,
    const float* __restrict__ Wm, const float* __restrict__ Ws,
    const float* __restrict__ bias, const float* __restrict__ wc, // wc + layer_row_off*16
    float4* hb4, float4* ab4, float* t16)
{
    constexpr int NCOL = OUTW / 2;
    __syncthreads();                       // [A] hb stable
    // gather agg[r][half*32 .. +32) from CSR, register-accumulated
    float ga[32];
    #pragma unroll
    for (int u = 0; u < 32; ++u) ga[u] = 0.f;
    const int cb = half * 8;
    for (int j = js; j < je; ++j) {
        const int cl = clp[j];
        const float w = wp[j];
        const int base = cl * 16, sw = cl & 15;
        #pragma unroll
        for (int u = 0; u < 8; ++u) {
            const float4 h4 = hb4[base + ((cb + u) ^ sw)];
            ga[u*4+0] += w * h4.x; ga[u*4+1] += w * h4.y;
            ga[u*4+2] += w * h4.z; ga[u*4+3] += w * h4.w;
        }
    }
    {
        const int base = r * 16, sw = r & 15;
        #pragma unroll
        for (int u = 0; u < 8; ++u) {
            float4 v; v.x = ga[u*4+0]; v.y = ga[u*4+1]; v.z = ga[u*4+2]; v.w = ga[u*4+3];
            ab4[base + ((cb + u) ^ sw)] = v;
        }
    }
    __syncthreads();                       // [B]
    // dense: h_next[r][j0..j0+NCOL) = relu(agg@Wm + h@Ws + b)
    const int j0 = half * NCOL;
    float acc[NCOL];
    #pragma unroll
    for (int jj = 0; jj < NCOL; ++jj) acc[jj] = bias[j0 + jj];
    const int rbase = r * 16, rsw = r & 15;
    for (int ic = 0; ic < 16; ++ic) {
        const float4 a4 = ab4[rbase + (ic ^ rsw)];
        const float4 h4 = hb4[rbase + (ic ^ rsw)];
        const float av[4] = {a4.x, a4.y, a4.z, a4.w};
        const float hv[4] = {h4.x, h4.y, h4.z, h4.w};
        #pragma unroll
        for (int u = 0; u < 4; ++u) {
            const int i = ic * 4 + u;
            const float a = av[u], h = hv[u];
            const float* wmr = Wm + i * OUTW + j0;
            const float* wsr = Ws + i * OUTW + j0;
            #pragma unroll
            for (int q4 = 0; q4 < NCOL / 4; ++q4) {
                const float4 wm4 = *(const float4*)(wmr + q4 * 4);
                const float4 ws4 = *(const float4*)(wsr + q4 * 4);
                acc[q4*4+0] += a * wm4.x + h * ws4.x;
                acc[q4*4+1] += a * wm4.y + h * ws4.y;
                acc[q4*4+2] += a * wm4.z + h * ws4.z;
                acc[q4*4+3] += a * wm4.w + h * ws4.w;
            }
        }
    }
    #pragma unroll
    for (int jj = 0; jj < NCOL; ++jj) acc[jj] = fmaxf(acc[jj], 0.f);
    __syncthreads();                       // [C] all hb/ab reads done
    if (WRITE_H) {
        const int base = r * 16, sw = r & 15;
        #pragma unroll
        for (int u = 0; u < NCOL / 4; ++u) {
            float4 v; v.x = acc[u*4+0]; v.y = acc[u*4+1]; v.z = acc[u*4+2]; v.w = acc[u*4+3];
            hb4[base + ((cb + u) ^ sw)] = v;
        }
    }
    // t16 += h_next @ Wc[layer rows]  (16-wide combined FC)
    #pragma unroll
    for (int jj = 0; jj < NCOL; ++jj) {
        const float hvv = acc[jj];
        const float* wr = wc + (j0 + jj) * 16;
        #pragma unroll
        for (int q4 = 0; q4 < 4; ++q4) {
            const float4 w4 = *(const float4*)(wr + q4 * 4);
            t16[q4*4+0] += hvv * w4.x;
            t16[q4*4+1] += hvv * w4.y;
            t16[q4*4+2] += hvv * w4.z;
            t16[q4*4+3] += hvv * w4.w;
        }
    }
}

// LDS (128.5 KB) already caps at 1 block/CU = 2 waves/EU; pin waves-per-eu to [2,2]
// so the register allocator budgets 256 VGPRs instead of the default 128 (which spilled).
__launch_bounds__(512)
__attribute__((amdgpu_waves_per_eu(2, 2)))
__global__ void gconv_kernel(
    const float* __restrict__ x,
    const float* __restrict__ Wm0, const float* __restrict__ Ws0, const float* __restrict__ b0,
    const float* __restrict__ Wm1, const float* __restrict__ Ws1, const float* __restrict__ b1,
    const float* __restrict__ Wm2, const float* __restrict__ Ws2, const float* __restrict__ b2,
    const float* __restrict__ wcomb, const float* __restrict__ bcomb,
    const float* __restrict__ wrec, const unsigned char* __restrict__ clrec,
    const int* __restrict__ indptr,
    float* __restrict__ out, float* __restrict__ entpart)
{
    __shared__ float4 hb4[4096];   // h tile, XOR-chunk-swizzled  (64 KB)
    __shared__ float4 ab4[4096];   // agg tile / t16 exchange     (64 KB)
    __shared__ float  red[8];
    float* ab = (float*)ab4;
    const int t = threadIdx.x;
    const int bid = blockIdx.x;
    const int d = bid >> 8;
    const int b = bid & (NB - 1);
    const int r = t & (NN - 1);
    const int half = t >> 8;
    const int lane = t & 63;
    const int wave = t >> 6;

    // stage x -> hb (swizzled)
    {
        const float4* xv = (const float4*)(x + (size_t)b * NN * HID);
        #pragma unroll
        for (int it = 0; it < 8; ++it) {
            const int idx = t + it * 512;
            const int nrow = idx >> 4, c = idx & 15;
            hb4[nrow * 16 + (c ^ (nrow & 15))] = xv[idx];
        }
    }
    float t16[16];
    #pragma unroll
    for (int q = 0; q < 16; ++q) t16[q] = 0.f;

    const float* wp = wrec + (size_t)d * NB * EPG + (size_t)b * EPG;
    const unsigned char* clp = clrec + (size_t)b * EPG;
    const int js = indptr[b * 257 + r];
    const int je = indptr[b * 257 + r + 1];

    layer_step<64, true >(t, r, half, js, je, wp, clp, Wm0 + d*HID*HID, Ws0 + d*HID*HID,
                          b0 + d*HID, wcomb,            hb4, ab4, t16);
    layer_step<64, true >(t, r, half, js, je, wp, clp, Wm1 + d*HID*HID, Ws1 + d*HID*HID,
                          b1 + d*HID, wcomb + 64*16,    hb4, ab4, t16);
    layer_step<16, false>(t, r, half, js, je, wp, clp, Wm2 + d*HID*KK,  Ws2 + d*HID*KK,
                          b2 + d*KK,  wcomb + 128*16,   hb4, ab4, t16);

    // exchange t16 halves via ab (layout [k][r]: 64 lanes hit 64 distinct banks 2-way)
    __syncthreads();
    if (half == 1) {
        #pragma unroll
        for (int k = 0; k < 16; ++k) ab[(k << 8) + r] = t16[k];
    }
    __syncthreads();
    float ent_local = 0.f;
    if (half == 0) {
        float logits[KK];
        #pragma unroll
        for (int k = 0; k < KK; ++k) logits[k] = t16[k] + ab[(k << 8) + r] + bcomb[k];
        float m = logits[0];
        #pragma unroll
        for (int k = 1; k < KK; ++k) m = fmaxf(m, logits[k]);
        float sum = 0.f, sv[KK];
        #pragma unroll
        for (int k = 0; k < KK; ++k) { sv[k] = expf(logits[k] - m); sum += sv[k]; }
        const float inv = 1.f / sum;
        float* sp = out + S_OFF + ((size_t)(d * NB + b) * NN + r) * KK;
        #pragma unroll
        for (int k = 0; k < KK; ++k) {
            const float s = sv[k] * inv;
            sp[k] = s;
            ent_local -= s * logf(s + 1e-15f);
        }
    }
    #pragma unroll
    for (int off = 32; off; off >>= 1) ent_local += __shfl_down(ent_local, off);
    if (lane == 0) red[wave] = ent_local;
    __syncthreads();
    if (t == 0) {
        float s = 0.f;
        #pragma unroll
        for (int w = 0; w < 8; ++w) s += red[w];
        entpart[bid] = s;
    }
}

// ---------------- pool: padj = sum_r s[r] (x) G[r], G = A s ; + mod + px ----------------
#define SSTR 20
__launch_bounds__(256)
__global__ void pool_kernel(
    const float* __restrict__ x_to_pool,
    const float* __restrict__ wrec, const unsigned char* __restrict__ clrec,
    const int* __restrict__ indptr,
    const float* __restrict__ out_s, float* __restrict__ out, float* __restrict__ modpart)
{
    __shared__ float sl[NN * SSTR];       // 20 KB
    __shared__ float gl[NN * SSTR];       // 20 KB
    __shared__ float padjw[4 * 256];      // per-wave partials (deterministic merge)
    __shared__ float red[4];
    const int t = threadIdx.x;
    const int bid = blockIdx.x;
    const int d = bid >> 8;
    const int b = bid & (NB - 1);
    const int lane = t & 63;
    const int wave = t >> 6;

    {
        const float4* sp4 = (const float4*)(out_s + S_OFF + (size_t)(d * NB + b) * NN * KK);
        #pragma unroll
        for (int it = 0; it < 4; ++it) {
            const int idx = t + it * 256;
            const int nrow = idx >> 2, c = idx & 3;
            *(float4*)(sl + nrow * SSTR + c * 4) = sp4[idx];
        }
    }
    __syncthreads();

    const float* wp = wrec + (size_t)d * NB * EPG + (size_t)b * EPG;
    const unsigned char* clp = clrec + (size_t)b * EPG;
    const int js = indptr[b * 257 + t];
    const int je = indptr[b * 257 + t + 1];
    float sr[16];
    {
        #pragma unroll
        for (int c = 0; c < 4; ++c) {
            const float4 v = *(const float4*)(sl + t * SSTR + c * 4);
            sr[c*4+0] = v.x; sr[c*4+1] = v.y; sr[c*4+2] = v.z; sr[c*4+3] = v.w;
        }
    }
    float g[16];
    #pragma unroll
    for (int k = 0; k < 16; ++k) g[k] = 0.f;
    float modacc = 0.f;
    for (int j = js; j < je; ++j) {
        const int cl = clp[j];
        const float w = wp[j];
        const float* srow = sl + cl * SSTR;
        float ss = 0.f;
        #pragma unroll
        for (int c = 0; c < 4; ++c) {
            const float4 sv = *(const float4*)(srow + c * 4);
            g[c*4+0] += w * sv.x; g[c*4+1] += w * sv.y;
            g[c*4+2] += w * sv.z; g[c*4+3] += w * sv.w;
            const float d0 = sr[c*4+0] - sv.x, d1 = sr[c*4+1] - sv.y;
            const float d2 = sr[c*4+2] - sv.z, d3 = sr[c*4+3] - sv.w;
            ss += d0*d0 + d1*d1 + d2*d2 + d3*d3;
        }
        modacc += w * ss;
    }
    {
        #pragma unroll
        for (int c = 0; c < 4; ++c) {
            float4 v; v.x = g[c*4+0]; v.y = g[c*4+1]; v.z = g[c*4+2]; v.w = g[c*4+3];
            *(float4*)(gl + t * SSTR + c * 4) = v;
        }
    }
    __syncthreads();

    // padj[k][l] = sum_r s[r][k] * G[r][l]; wave w covers r in [w*64, w*64+64)
    {
        const int k = t & 15, lg = (t >> 4) & 3;
        float p0 = 0.f, p1 = 0.f, p2 = 0.f, p3 = 0.f;
        const int r0 = wave * 64;
        for (int rr = r0; rr < r0 + 64; ++rr) {
            const float sk = sl[rr * SSTR + k];
            const float4 g4 = *(const float4*)(gl + rr * SSTR + lg * 4);
            p0 += sk * g4.x; p1 += sk * g4.y; p2 += sk * g4.z; p3 += sk * g4.w;
        }
        float* pw = padjw + wave * 256 + k * 16 + lg * 4;
        pw[0] = p0; pw[1] = p1; pw[2] = p2; pw[3] = p3;
    }

    // px[k][f] = sum_n s[n][k] * xtp[n][f*3+d]
    {
        const int f = t & 63;
        const int kg = t >> 6;
        float xa0 = 0.f, xa1 = 0.f, xa2 = 0.f, xa3 = 0.f;
        const float* xp = x_to_pool + (size_t)b * NN * (64 * DIMS) + f * DIMS + d;
        #pragma unroll 4
        for (int nn2 = 0; nn2 < NN; ++nn2) {
            const float xv = xp[(size_t)nn2 * (64 * DIMS)];
            const float4 s4 = *(const float4*)(sl + nn2 * SSTR + kg * 4);
            xa0 += xv * s4.x; xa1 += xv * s4.y; xa2 += xv * s4.z; xa3 += xv * s4.w;
        }
        const float sc = 1.f / 16.f;  // K/N
        out[PX_OFF + ((size_t)((b * KK + kg * 4 + 0) * 64) + f) * DIMS + d] = xa0 * sc;
        out[PX_OFF + ((size_t)((b * KK + kg * 4 + 1) * 64) + f) * DIMS + d] = xa1 * sc;
        out[PX_OFF + ((size_t)((b * KK + kg * 4 + 2) * 64) + f) * DIMS + d] = xa2 * sc;
        out[PX_OFF + ((size_t)((b * KK + kg * 4 + 3) * 64) + f) * DIMS + d] = xa3 * sc;
    }

    #pragma unroll
    for (int off = 32; off; off >>= 1) modacc += __shfl_down(modacc, off);
    if (lane == 0) red[wave] = modacc;
    __syncthreads();   // also fences padjw
    if (t == 0) modpart[bid] = red[0] + red[1] + red[2] + red[3];

    {
        const float v = (padjw[t] + padjw[256 + t] + padjw[512 + t] + padjw[768 + t]) * (1.f / 256.f);
        out[PEA_OFF + (size_t)((b * KK + (t >> 4)) * KK + (t & 15)) * DIMS + d] = v;
    }
}

__global__ void aux_kernel(float* __restrict__ out)
{
    const int idx = blockIdx.x * 256 + threadIdx.x;
    if (idx < 2 * NTOT) {
        const int r = idx & (NTOT - 1);
        const int bb = r >> 8;
        const int j = r & 255;
        const int v = (idx < NTOT) ? (bb * KK + (j >> 4)) : (bb * KK + (j & 15));
        out[PEI_OFF + idx] = (float)v;
    } else if (idx < 2 * NTOT + NB * KK) {
        const int i = idx - 2 * NTOT;
        out[PB_OFF + i] = (float)(i >> 4);
    }
}

__global__ void loss_kernel(const float* __restrict__ entpart,
                            const float* __restrict__ modpart,
                            float* __restrict__ out)
{
    const int tid = threadIdx.x;
    float e = 0.f, m = 0.f;
    for (int i = tid; i < DIMS * NB; i += 256) { e += entpart[i]; m += modpart[i]; }
    #pragma unroll
    for (int off = 32; off; off >>= 1) { e += __shfl_down(e, off); m += __shfl_down(m, off); }
    __shared__ float er[4], mr[4];
    const int wave = tid >> 6, lane = tid & 63;
    if (lane == 0) { er[wave] = e; mr[wave] = m; }
    __syncthreads();
    if (tid == 0) {
        const float es = er[0] + er[1] + er[2] + er[3];
        const float ms = mr[0] + mr[1] + mr[2] + mr[3];
        out[LOSS_OFF] = ms / (float)NE + es / (float)(DIMS * NTOT);
    }
}

extern "C" void kernel_launch(void* const* d_in, const int* in_sizes, int n_in,
                              void* d_out, int out_size, void* d_ws, size_t ws_size,
                              hipStream_t stream)
{
    const float* x         = (const float*)d_in[0];
    const float* edge_attr = (const float*)d_in[1];
    const float* x_to_pool = (const float*)d_in[2];
    const float* Wm0 = (const float*)d_in[3];
    const float* Ws0 = (const float*)d_in[4];
    const float* b0  = (const float*)d_in[5];
    const float* Wm1 = (const float*)d_in[6];
    const float* Ws1 = (const float*)d_in[7];
    const float* b1  = (const float*)d_in[8];
    const float* Wm2 = (const float*)d_in[9];
    const float* Ws2 = (const float*)d_in[10];
    const float* b2  = (const float*)d_in[11];
    const float* fcW1= (const float*)d_in[12];
    const float* fcb1= (const float*)d_in[13];
    const float* fcW2= (const float*)d_in[14];
    const float* fcb2= (const float*)d_in[15];
    const int* edge_index = (const int*)d_in[16];
    float* out = (float*)d_out;
    char* ws = (char*)d_ws;
    float*         wrec  = (float*)(ws + WREC_WS);
    unsigned char* clrec = (unsigned char*)(ws + CLREC_WS);
    int*           iptr  = (int*)(ws + IPTR_WS);
    float*         entpart = (float*)(ws + ENT_WS);
    float*         modpart = (float*)(ws + MOD_WS);
    float*         wc    = (float*)(ws + WC_WS);
    float*         bc    = (float*)(ws + BC_WS);

    csr_build<<<dim3(NB), dim3(256), 0, stream>>>(edge_index, edge_attr, wrec, clrec, iptr);
    fc_combine<<<dim3(1), dim3(256), 0, stream>>>(fcW1, fcb1, fcW2, fcb2, wc, bc);
    gconv_kernel<<<dim3(DIMS * NB), dim3(512), 0, stream>>>(
        x, Wm0, Ws0, b0, Wm1, Ws1, b1, Wm2, Ws2, b2,
        wc, bc, wrec, clrec, iptr, out, entpart);
    pool_kernel<<<dim3(DIMS * NB), dim3(256), 0, stream>>>(
        x_to_pool, wrec, clrec, iptr, out, out, modpart);
    aux_kernel<<<dim3((2 * NTOT + NB * KK + 255) / 256), dim3(256), 0, stream>>>(out);
    loss_kernel<<<dim3(1), dim3(256), 0, stream>>>(entpart, modpart, out);
}

// Round 6
// 2094.174 us; speedup vs baseline: 1.0091x; 1.0071x over previous
//
#include <hip/hip_runtime.h>

#define DIMS 3
#define NB 256
#define NN 256
#define KK 16
#define HID 64
#define EPG 8192
#define NTOT (NB*NN)
#define NE (NB*EPG)

// d_out layout (flat concat of reference outputs, all as float)
#define PX_OFF   0          // (B*K, F, DIMS)           = 786432
#define PEI_OFF  786432     // (2, B*K*K)               = 131072
#define PEA_OFF  917504     // (B*K*K, DIMS)            = 196608
#define PB_OFF   1114112    // (B*K,)                   = 4096
#define LOSS_OFF 1118208    // scalar
#define S_OFF    1118209    // (DIMS, B, N, K)          = 3145728

// d_ws layout (bytes) — total ~27.5 MB
#define WREC_WS  0                 // float[3][NB*EPG] per-d edge weight (CSR order) = 24 MB
#define CLREC_WS 25165824          // uchar[NB*EPG] col-local index
#define IPTR_WS  27262976          // int[NB*257]
#define ENT_WS   27526144          // float[768]
#define MOD_WS   27529216          // float[768]
#define WC_WS    27532288          // float[144*16]  (fcW1 @ fcW2)
#define BC_WS    27541504          // float[16]      (fcb1 @ fcW2 + fcb2)

// ---------------- combined FC weights: Wc = fcW1@fcW2, bc = fcb1@fcW2+fcb2 ----------------
__global__ void fc_combine(const float* __restrict__ fcW1, const float* __restrict__ fcb1,
                           const float* __restrict__ fcW2, const float* __restrict__ fcb2,
                           float* __restrict__ wc, float* __restrict__ bc)
{
    const int t = threadIdx.x;
    for (int idx = t; idx < 144 * 16; idx += 256) {
        const int i = idx >> 4, k = idx & 15;
        float s = 0.f;
        for (int q = 0; q < 50; ++q) s += fcW1[i * 50 + q] * fcW2[q * 16 + k];
        wc[idx] = s;
    }
    if (t < 16) {
        float s = fcb2[t];
        for (int q = 0; q < 50; ++q) s += fcb1[q] * fcW2[q * 16 + t];
        bc[t] = s;
    }
}

// ---------------- CSR build (deterministic stable counting sort) ----------------
__launch_bounds__(256)
__global__ void csr_build(const int* __restrict__ edge_index,
                          const float* __restrict__ edge_attr,
                          float* __restrict__ wrec, unsigned char* __restrict__ clrec,
                          int* __restrict__ indptr)
{
    __shared__ int rl[EPG];              // 32 KB
    __shared__ unsigned char clb[EPG];   // 8 KB
    __shared__ int cnt[256];
    __shared__ int sc[256];
    const int b = blockIdx.x;
    const int t = threadIdx.x;
    const int* rowp = edge_index + (size_t)b * EPG;
    const int* colp = edge_index + (size_t)NB * EPG + (size_t)b * EPG;
    for (int i = t; i < EPG; i += 256) {
        rl[i] = rowp[i] & (NN - 1);
        clb[i] = (unsigned char)(colp[i] & (NN - 1));
    }
    cnt[t] = 0;
    __syncthreads();
    for (int i = t; i < EPG; i += 256) atomicAdd(&cnt[rl[i]], 1);
    __syncthreads();
    sc[t] = cnt[t];
    __syncthreads();
    for (int ofs = 1; ofs < 256; ofs <<= 1) {
        int v = (t >= ofs) ? sc[t - ofs] : 0;
        __syncthreads();
        sc[t] += v;
        __syncthreads();
    }
    const int start = sc[t] - cnt[t];
    indptr[b * 257 + t] = start;
    if (t == 255) indptr[b * 257 + 256] = EPG;
    // stable claim: scan edges in order; thread t takes its row's edges
    const float* eap = edge_attr + (size_t)b * EPG * 3;
    float* w0 = wrec + (size_t)b * EPG;
    float* w1 = wrec + (size_t)NB * EPG + (size_t)b * EPG;
    float* w2 = wrec + 2 * (size_t)NB * EPG + (size_t)b * EPG;
    unsigned char* cdst = clrec + (size_t)b * EPG;
    int c = start;
    for (int e4 = 0; e4 < EPG; e4 += 4) {
        const int4 r4 = *(const int4*)&rl[e4];
        const int rv[4] = {r4.x, r4.y, r4.z, r4.w};
        #pragma unroll
        for (int u = 0; u < 4; ++u) {
            if (rv[u] == t) {
                const int e = e4 + u;
                w0[c] = eap[e * 3 + 0];
                w1[c] = eap[e * 3 + 1];
                w2[c] = eap[e * 3 + 2];
                cdst[c] = clb[e];
                ++c;
            }
        }
    }
}

// -------- gconv: 3 layers + combined FC + softmax fused; 1024 thr = (row, quarter) --------
// Per-thread state: ga[16] (gather), acc[<=16] (dense), t16[16] (FC acc) -> no spill at 128 VGPR.
template<int OUTW, bool WRITE_H>
__device__ __forceinline__ void layer_step(
    int r, int q, int js, int je,
    const float* __restrict__ wp, const unsigned char* __restrict__ clp,
    const float* __restrict__ Wm, const float* __restrict__ Ws,
    const float* __restrict__ bias, const float* __restrict__ wc, // wc + layer_row_off*16
    float4* hb4, float4* ab4, float* t16)
{
    constexpr int NCOL = OUTW / 4;         // outputs per thread: 16 (L0/L1), 4 (L2)
    __syncthreads();                       // [A] hb stable
    // gather agg[r][q*16 .. +16) from CSR, register-accumulated (4 float4 chunks)
    float ga[16];
    #pragma unroll
    for (int u = 0; u < 16; ++u) ga[u] = 0.f;
    const int cb = q * 4;                  // float4 chunk base
    for (int j = js; j < je; ++j) {
        const int cl = clp[j];
        const float w = wp[j];
        const int base = cl * 16, sw = cl & 15;
        #pragma unroll
        for (int u = 0; u < 4; ++u) {
            const float4 h4 = hb4[base + ((cb + u) ^ sw)];
            ga[u*4+0] += w * h4.x; ga[u*4+1] += w * h4.y;
            ga[u*4+2] += w * h4.z; ga[u*4+3] += w * h4.w;
        }
    }
    {
        const int base = r * 16, sw = r & 15;
        #pragma unroll
        for (int u = 0; u < 4; ++u) {
            float4 v; v.x = ga[u*4+0]; v.y = ga[u*4+1]; v.z = ga[u*4+2]; v.w = ga[u*4+3];
            ab4[base + ((cb + u) ^ sw)] = v;
        }
    }
    __syncthreads();                       // [B]
    // dense: h_next[r][j0..j0+NCOL) = relu(agg@Wm + h@Ws + b), all 64 inputs from LDS
    const int j0 = q * NCOL;
    float acc[NCOL];
    #pragma unroll
    for (int jj = 0; jj < NCOL; ++jj) acc[jj] = bias[j0 + jj];
    const int rbase = r * 16, rsw = r & 15;
    for (int ic = 0; ic < 16; ++ic) {
        const float4 a4 = ab4[rbase + (ic ^ rsw)];
        const float4 h4 = hb4[rbase + (ic ^ rsw)];
        const float av[4] = {a4.x, a4.y, a4.z, a4.w};
        const float hv[4] = {h4.x, h4.y, h4.z, h4.w};
        #pragma unroll
        for (int u = 0; u < 4; ++u) {
            const int i = ic * 4 + u;
            const float a = av[u], h = hv[u];
            const float* wmr = Wm + i * OUTW + j0;
            const float* wsr = Ws + i * OUTW + j0;
            #pragma unroll
            for (int q4 = 0; q4 < NCOL / 4; ++q4) {
                const float4 wm4 = *(const float4*)(wmr + q4 * 4);
                const float4 ws4 = *(const float4*)(wsr + q4 * 4);
                acc[q4*4+0] += a * wm4.x + h * ws4.x;
                acc[q4*4+1] += a * wm4.y + h * ws4.y;
                acc[q4*4+2] += a * wm4.z + h * ws4.z;
                acc[q4*4+3] += a * wm4.w + h * ws4.w;
            }
        }
    }
    #pragma unroll
    for (int jj = 0; jj < NCOL; ++jj) acc[jj] = fmaxf(acc[jj], 0.f);
    __syncthreads();                       // [C] all hb/ab reads done
    if (WRITE_H) {
        const int base = r * 16, sw = r & 15;
        #pragma unroll
        for (int u = 0; u < NCOL / 4; ++u) {
            float4 v; v.x = acc[u*4+0]; v.y = acc[u*4+1]; v.z = acc[u*4+2]; v.w = acc[u*4+3];
            hb4[base + ((cb + u) ^ sw)] = v;
        }
    }
    // t16 += h_next_cols @ Wc[layer rows j0..j0+NCOL)
    #pragma unroll
    for (int jj = 0; jj < NCOL; ++jj) {
        const float hvv = acc[jj];
        const float* wr = wc + (j0 + jj) * 16;
        #pragma unroll
        for (int q4 = 0; q4 < 4; ++q4) {
            const float4 w4 = *(const float4*)(wr + q4 * 4);
            t16[q4*4+0] += hvv * w4.x;
            t16[q4*4+1] += hvv * w4.y;
            t16[q4*4+2] += hvv * w4.z;
            t16[q4*4+3] += hvv * w4.w;
        }
    }
}

__launch_bounds__(1024)
__global__ void gconv_kernel(
    const float* __restrict__ x,
    const float* __restrict__ Wm0, const float* __restrict__ Ws0, const float* __restrict__ b0,
    const float* __restrict__ Wm1, const float* __restrict__ Ws1, const float* __restrict__ b1,
    const float* __restrict__ Wm2, const float* __restrict__ Ws2, const float* __restrict__ b2,
    const float* __restrict__ wcomb, const float* __restrict__ bcomb,
    const float* __restrict__ wrec, const unsigned char* __restrict__ clrec,
    const int* __restrict__ indptr,
    float* __restrict__ out, float* __restrict__ entpart)
{
    __shared__ float4 hb4[4096];   // h tile, XOR-chunk-swizzled  (64 KB)
    __shared__ float4 ab4[4096];   // agg tile / t16 exchange     (64 KB)
    __shared__ float  red[16];
    float* ab = (float*)ab4;
    const int t = threadIdx.x;
    const int bid = blockIdx.x;
    const int d = bid >> 8;
    const int b = bid & (NB - 1);
    const int r = t & (NN - 1);
    const int q = t >> 8;          // quarter: 16 channels / 16 (or 4) outputs each
    const int lane = t & 63;
    const int wave = t >> 6;

    // stage x -> hb (swizzled)
    {
        const float4* xv = (const float4*)(x + (size_t)b * NN * HID);
        #pragma unroll
        for (int it = 0; it < 4; ++it) {
            const int idx = t + it * 1024;
            const int nrow = idx >> 4, c = idx & 15;
            hb4[nrow * 16 + (c ^ (nrow & 15))] = xv[idx];
        }
    }
    float t16[16];
    #pragma unroll
    for (int k = 0; k < 16; ++k) t16[k] = 0.f;

    const float* wp = wrec + (size_t)d * NB * EPG + (size_t)b * EPG;
    const unsigned char* clp = clrec + (size_t)b * EPG;
    const int js = indptr[b * 257 + r];
    const int je = indptr[b * 257 + r + 1];

    layer_step<64, true >(r, q, js, je, wp, clp, Wm0 + d*HID*HID, Ws0 + d*HID*HID,
                          b0 + d*HID, wcomb,            hb4, ab4, t16);
    layer_step<64, true >(r, q, js, je, wp, clp, Wm1 + d*HID*HID, Ws1 + d*HID*HID,
                          b1 + d*HID, wcomb + 64*16,    hb4, ab4, t16);
    layer_step<16, false>(r, q, js, je, wp, clp, Wm2 + d*HID*KK,  Ws2 + d*HID*KK,
                          b2 + d*KK,  wcomb + 128*16,   hb4, ab4, t16);

    // 4-way t16 reduction via ab: region q -> [q*4096 + k*256 + r]
    __syncthreads();
    #pragma unroll
    for (int k = 0; k < 16; ++k) ab[q * 4096 + (k << 8) + r] = t16[k];
    __syncthreads();
    float ent_local = 0.f;
    if (q == 0) {
        float logits[KK];
        #pragma unroll
        for (int k = 0; k < KK; ++k)
            logits[k] = t16[k] + ab[4096 + (k << 8) + r] + ab[8192 + (k << 8) + r]
                      + ab[12288 + (k << 8) + r] + bcomb[k];
        float m = logits[0];
        #pragma unroll
        for (int k = 1; k < KK; ++k) m = fmaxf(m, logits[k]);
        float sum = 0.f, sv[KK];
        #pragma unroll
        for (int k = 0; k < KK; ++k) { sv[k] = expf(logits[k] - m); sum += sv[k]; }
        const float inv = 1.f / sum;
        float* sp = out + S_OFF + ((size_t)(d * NB + b) * NN + r) * KK;
        #pragma unroll
        for (int k = 0; k < KK; ++k) {
            const float s = sv[k] * inv;
            sp[k] = s;
            ent_local -= s * logf(s + 1e-15f);
        }
    }
    #pragma unroll
    for (int off = 32; off; off >>= 1) ent_local += __shfl_down(ent_local, off);
    if (lane == 0) red[wave] = ent_local;
    __syncthreads();
    if (t == 0) {
        float s = 0.f;
        #pragma unroll
        for (int w = 0; w < 16; ++w) s += red[w];
        entpart[bid] = s;
    }
}

// ---------------- pool: padj = sum_r s[r] (x) G[r], G = A s ; + mod + px ----------------
#define SSTR 20
__launch_bounds__(256)
__global__ void pool_kernel(
    const float* __restrict__ x_to_pool,
    const float* __restrict__ wrec, const unsigned char* __restrict__ clrec,
    const int* __restrict__ indptr,
    const float* __restrict__ out_s, float* __restrict__ out, float* __restrict__ modpart)
{
    __shared__ float sl[NN * SSTR];       // 20 KB
    __shared__ float gl[NN * SSTR];       // 20 KB
    __shared__ float padjw[4 * 256];      // per-wave partials (deterministic merge)
    __shared__ float red[4];
    const int t = threadIdx.x;
    const int bid = blockIdx.x;
    const int d = bid >> 8;
    const int b = bid & (NB - 1);
    const int lane = t & 63;
    const int wave = t >> 6;

    {
        const float4* sp4 = (const float4*)(out_s + S_OFF + (size_t)(d * NB + b) * NN * KK);
        #pragma unroll
        for (int it = 0; it < 4; ++it) {
            const int idx = t + it * 256;
            const int nrow = idx >> 2, c = idx & 3;
            *(float4*)(sl + nrow * SSTR + c * 4) = sp4[idx];
        }
    }
    __syncthreads();

    const float* wp = wrec + (size_t)d * NB * EPG + (size_t)b * EPG;
    const unsigned char* clp = clrec + (size_t)b * EPG;
    const int js = indptr[b * 257 + t];
    const int je = indptr[b * 257 + t + 1];
    float sr[16];
    {
        #pragma unroll
        for (int c = 0; c < 4; ++c) {
            const float4 v = *(const float4*)(sl + t * SSTR + c * 4);
            sr[c*4+0] = v.x; sr[c*4+1] = v.y; sr[c*4+2] = v.z; sr[c*4+3] = v.w;
        }
    }
    float g[16];
    #pragma unroll
    for (int k = 0; k < 16; ++k) g[k] = 0.f;
    float modacc = 0.f;
    for (int j = js; j < je; ++j) {
        const int cl = clp[j];
        const float w = wp[j];
        const float* srow = sl + cl * SSTR;
        float ss = 0.f;
        #pragma unroll
        for (int c = 0; c < 4; ++c) {
            const float4 sv = *(const float4*)(srow + c * 4);
            g[c*4+0] += w * sv.x; g[c*4+1] += w * sv.y;
            g[c*4+2] += w * sv.z; g[c*4+3] += w * sv.w;
            const float d0 = sr[c*4+0] - sv.x, d1 = sr[c*4+1] - sv.y;
            const float d2 = sr[c*4+2] - sv.z, d3 = sr[c*4+3] - sv.w;
            ss += d0*d0 + d1*d1 + d2*d2 + d3*d3;
        }
        modacc += w * ss;
    }
    {
        #pragma unroll
        for (int c = 0; c < 4; ++c) {
            float4 v; v.x = g[c*4+0]; v.y = g[c*4+1]; v.z = g[c*4+2]; v.w = g[c*4+3];
            *(float4*)(gl + t * SSTR + c * 4) = v;
        }
    }
    __syncthreads();

    // padj[k][l] = sum_r s[r][k] * G[r][l]; wave w covers r in [w*64, w*64+64)
    {
        const int k = t & 15, lg = (t >> 4) & 3;
        float p0 = 0.f, p1 = 0.f, p2 = 0.f, p3 = 0.f;
        const int r0 = wave * 64;
        for (int rr = r0; rr < r0 + 64; ++rr) {
            const float sk = sl[rr * SSTR + k];
            const float4 g4 = *(const float4*)(gl + rr * SSTR + lg * 4);
            p0 += sk * g4.x; p1 += sk * g4.y; p2 += sk * g4.z; p3 += sk * g4.w;
        }
        float* pw = padjw + wave * 256 + k * 16 + lg * 4;
        pw[0] = p0; pw[1] = p1; pw[2] = p2; pw[3] = p3;
    }

    // px[k][f] = sum_n s[n][k] * xtp[n][f*3+d]
    {
        const int f = t & 63;
        const int kg = t >> 6;
        float xa0 = 0.f, xa1 = 0.f, xa2 = 0.f, xa3 = 0.f;
        const float* xp = x_to_pool + (size_t)b * NN * (64 * DIMS) + f * DIMS + d;
        #pragma unroll 4
        for (int nn2 = 0; nn2 < NN; ++nn2) {
            const float xv = xp[(size_t)nn2 * (64 * DIMS)];
            const float4 s4 = *(const float4*)(sl + nn2 * SSTR + kg * 4);
            xa0 += xv * s4.x; xa1 += xv * s4.y; xa2 += xv * s4.z; xa3 += xv * s4.w;
        }
        const float sc = 1.f / 16.f;  // K/N
        out[PX_OFF + ((size_t)((b * KK + kg * 4 + 0) * 64) + f) * DIMS + d] = xa0 * sc;
        out[PX_OFF + ((size_t)((b * KK + kg * 4 + 1) * 64) + f) * DIMS + d] = xa1 * sc;
        out[PX_OFF + ((size_t)((b * KK + kg * 4 + 2) * 64) + f) * DIMS + d] = xa2 * sc;
        out[PX_OFF + ((size_t)((b * KK + kg * 4 + 3) * 64) + f) * DIMS + d] = xa3 * sc;
    }

    #pragma unroll
    for (int off = 32; off; off >>= 1) modacc += __shfl_down(modacc, off);
    if (lane == 0) red[wave] = modacc;
    __syncthreads();   // also fences padjw
    if (t == 0) modpart[bid] = red[0] + red[1] + red[2] + red[3];

    {
        const float v = (padjw[t] + padjw[256 + t] + padjw[512 + t] + padjw[768 + t]) * (1.f / 256.f);
        out[PEA_OFF + (size_t)((b * KK + (t >> 4)) * KK + (t & 15)) * DIMS + d] = v;
    }
}

__global__ void aux_kernel(float* __restrict__ out)
{
    const int idx = blockIdx.x * 256 + threadIdx.x;
    if (idx < 2 * NTOT) {
        const int r = idx & (NTOT - 1);
        const int bb = r >> 8;
        const int j = r & 255;
        const int v = (idx < NTOT) ? (bb * KK + (j >> 4)) : (bb * KK + (j & 15));
        out[PEI_OFF + idx] = (float)v;
    } else if (idx < 2 * NTOT + NB * KK) {
        const int i = idx - 2 * NTOT;
        out[PB_OFF + i] = (float)(i >> 4);
    }
}

__global__ void loss_kernel(const float* __restrict__ entpart,
                            const float* __restrict__ modpart,
                            float* __restrict__ out)
{
    const int tid = threadIdx.x;
    float e = 0.f, m = 0.f;
    for (int i = tid; i < DIMS * NB; i += 256) { e += entpart[i]; m += modpart[i]; }
    #pragma unroll
    for (int off = 32; off; off >>= 1) { e += __shfl_down(e, off); m += __shfl_down(m, off); }
    __shared__ float er[4], mr[4];
    const int wave = tid >> 6, lane = tid & 63;
    if (lane == 0) { er[wave] = e; mr[wave] = m; }
    __syncthreads();
    if (tid == 0) {
        const float es = er[0] + er[1] + er[2] + er[3];
        const float ms = mr[0] + mr[1] + mr[2] + mr[3];
        out[LOSS_OFF] = ms / (float)NE + es / (float)(DIMS * NTOT);
    }
}

extern "C" void kernel_launch(void* const* d_in, const int* in_sizes, int n_in,
                              void* d_out, int out_size, void* d_ws, size_t ws_size,
                              hipStream_t stream)
{
    const float* x         = (const float*)d_in[0];
    const float* edge_attr = (const float*)d_in[1];
    const float* x_to_pool = (const float*)d_in[2];
    const float* Wm0 = (const float*)d_in[3];
    const float* Ws0 = (const float*)d_in[4];
    const float* b0  = (const float*)d_in[5];
    const float* Wm1 = (const float*)d_in[6];
    const float* Ws1 = (const float*)d_in[7];
    const float* b1  = (const float*)d_in[8];
    const float* Wm2 = (const float*)d_in[9];
    const float* Ws2 = (const float*)d_in[10];
    const float* b2  = (const float*)d_in[11];
    const float* fcW1= (const float*)d_in[12];
    const float* fcb1= (const float*)d_in[13];
    const float* fcW2= (const float*)d_in[14];
    const float* fcb2= (const float*)d_in[15];
    const int* edge_index = (const int*)d_in[16];
    float* out = (float*)d_out;
    char* ws = (char*)d_ws;
    float*         wrec  = (float*)(ws + WREC_WS);
    unsigned char* clrec = (unsigned char*)(ws + CLREC_WS);
    int*           iptr  = (int*)(ws + IPTR_WS);
    float*         entpart = (float*)(ws + ENT_WS);
    float*         modpart = (float*)(ws + MOD_WS);
    float*         wc    = (float*)(ws + WC_WS);
    float*         bc    = (float*)(ws + BC_WS);

    csr_build<<<dim3(NB), dim3(256), 0, stream>>>(edge_index, edge_attr, wrec, clrec, iptr);
    fc_combine<<<dim3(1), dim3(256), 0, stream>>>(fcW1, fcb1, fcW2, fcb2, wc, bc);
    gconv_kernel<<<dim3(DIMS * NB), dim3(1024), 0, stream>>>(
        x, Wm0, Ws0, b0, Wm1, Ws1, b1, Wm2, Ws2, b2,
        wc, bc, wrec, clrec, iptr, out, entpart);
    pool_kernel<<<dim3(DIMS * NB), dim3(256), 0, stream>>>(
        x_to_pool, wrec, clrec, iptr, out, out, modpart);
    aux_kernel<<<dim3((2 * NTOT + NB * KK + 255) / 256), dim3(256), 0, stream>>>(out);
    loss_kernel<<<dim3(1), dim3(256), 0, stream>>>(entpart, modpart, out);
}

// Round 7
// 1051.034 us; speedup vs baseline: 2.0107x; 1.9925x over previous
//
#include <hip/hip_runtime.h>

#define DIMS 3
#define NB 256
#define NN 256
#define KK 16
#define HID 64
#define EPG 8192
#define NTOT (NB*NN)
#define NE (NB*EPG)

// d_out layout (flat concat of reference outputs, all as float)
#define PX_OFF   0          // (B*K, F, DIMS)           = 786432
#define PEI_OFF  786432     // (2, B*K*K)               = 131072
#define PEA_OFF  917504     // (B*K*K, DIMS)            = 196608
#define PB_OFF   1114112    // (B*K,)                   = 4096
#define LOSS_OFF 1118208    // scalar
#define S_OFF    1118209    // (DIMS, B, N, K)          = 3145728

// d_ws layout (bytes) — total ~27.5 MB
#define WREC_WS  0                 // float[3][NB*EPG] per-d edge weight (CSR order) = 24 MB
#define CLREC_WS 25165824          // uchar[NB*EPG] col-local index
#define IPTR_WS  27262976          // int[NB*257]
#define ENT_WS   27526144          // float[768]
#define MOD_WS   27529216          // float[768]
#define WC_WS    27532288          // float[144*16]  (fcW1 @ fcW2)
#define BC_WS    27541504          // float[16]      (fcb1 @ fcW2 + fcb2)

// ---------------- combined FC weights: Wc = fcW1@fcW2, bc = fcb1@fcW2+fcb2 ----------------
__global__ void fc_combine(const float* __restrict__ fcW1, const float* __restrict__ fcb1,
                           const float* __restrict__ fcW2, const float* __restrict__ fcb2,
                           float* __restrict__ wc, float* __restrict__ bc)
{
    const int t = threadIdx.x;
    for (int idx = t; idx < 144 * 16; idx += 256) {
        const int i = idx >> 4, k = idx & 15;
        float s = 0.f;
        for (int q = 0; q < 50; ++q) s += fcW1[i * 50 + q] * fcW2[q * 16 + k];
        wc[idx] = s;
    }
    if (t < 16) {
        float s = fcb2[t];
        for (int q = 0; q < 50; ++q) s += fcb1[q] * fcW2[q * 16 + t];
        bc[t] = s;
    }
}

// ---------------- CSR build (deterministic stable counting sort) ----------------
__launch_bounds__(256)
__global__ void csr_build(const int* __restrict__ edge_index,
                          const float* __restrict__ edge_attr,
                          float* __restrict__ wrec, unsigned char* __restrict__ clrec,
                          int* __restrict__ indptr)
{
    __shared__ int rl[EPG];              // 32 KB
    __shared__ unsigned char clb[EPG];   // 8 KB
    __shared__ int cnt[256];
    __shared__ int sc[256];
    const int b = blockIdx.x;
    const int t = threadIdx.x;
    const int* rowp = edge_index + (size_t)b * EPG;
    const int* colp = edge_index + (size_t)NB * EPG + (size_t)b * EPG;
    for (int i = t; i < EPG; i += 256) {
        rl[i] = rowp[i] & (NN - 1);
        clb[i] = (unsigned char)(colp[i] & (NN - 1));
    }
    cnt[t] = 0;
    __syncthreads();
    for (int i = t; i < EPG; i += 256) atomicAdd(&cnt[rl[i]], 1);
    __syncthreads();
    sc[t] = cnt[t];
    __syncthreads();
    for (int ofs = 1; ofs < 256; ofs <<= 1) {
        int v = (t >= ofs) ? sc[t - ofs] : 0;
        __syncthreads();
        sc[t] += v;
        __syncthreads();
    }
    const int start = sc[t] - cnt[t];
    indptr[b * 257 + t] = start;
    if (t == 255) indptr[b * 257 + 256] = EPG;
    // stable claim: scan edges in order; thread t takes its row's edges
    const float* eap = edge_attr + (size_t)b * EPG * 3;
    float* w0 = wrec + (size_t)b * EPG;
    float* w1 = wrec + (size_t)NB * EPG + (size_t)b * EPG;
    float* w2 = wrec + 2 * (size_t)NB * EPG + (size_t)b * EPG;
    unsigned char* cdst = clrec + (size_t)b * EPG;
    int c = start;
    for (int e4 = 0; e4 < EPG; e4 += 4) {
        const int4 r4 = *(const int4*)&rl[e4];
        const int rv[4] = {r4.x, r4.y, r4.z, r4.w};
        #pragma unroll
        for (int u = 0; u < 4; ++u) {
            if (rv[u] == t) {
                const int e = e4 + u;
                w0[c] = eap[e * 3 + 0];
                w1[c] = eap[e * 3 + 1];
                w2[c] = eap[e * 3 + 2];
                cdst[c] = clb[e];
                ++c;
            }
        }
    }
}

// -------- gconv: thread = (row r, quarter q) = ((t>>2), (t&3)); no persistent per-thread
// arrays (FC logits accumulate in LDS via single-owner RMW). One h buffer (agg overwrites h
// mid-layer). Weights staged in LDS. Peak live regs ~50 -> no scratch at any VGPR budget. --------
template<int OUTW, bool WRITE_H>
__device__ __forceinline__ void layer_step(
    int t, int r, int q, int js, int je,
    const float* __restrict__ wp, const unsigned char* __restrict__ clp,
    const float* __restrict__ Wm, const float* __restrict__ Ws,
    const float* __restrict__ bias, const float* __restrict__ wc, // wc + layer_row_off*16
    float4* hb4, float* wlds, float* lgl)
{
    constexpr int NCOL = OUTW / 4;            // dense outputs per thread (16 or 4)
    constexpr int NF4  = 64 * OUTW / 4;       // float4 count of one weight matrix
    // stage Wm,Ws -> LDS (prev layer's wlds reads ended before its last barrier)
    {
        const float4* wmv = (const float4*)Wm;
        const float4* wsv = (const float4*)Ws;
        float4* dm = (float4*)wlds;
        float4* ds = dm + NF4;
        for (int i = t; i < NF4; i += 1024) dm[i] = wmv[i];
        for (int i = t; i < NF4; i += 1024) ds[i] = wsv[i];
    }
    __syncthreads();                          // [B0] h stable + weights visible
    // P1: gather ga[16] (channels q*16..+16) over this row's CSR edges
    float ga[16];
    #pragma unroll
    for (int u = 0; u < 16; ++u) ga[u] = 0.f;
    const int cb = q * 4;
    for (int j = js; j < je; ++j) {
        const int cl = clp[j];
        const float w = wp[j];
        const int base = cl * 16, sw = cl & 15;
        #pragma unroll
        for (int u = 0; u < 4; ++u) {
            const float4 h4 = hb4[base + ((cb + u) ^ sw)];
            ga[u*4+0] += w * h4.x; ga[u*4+1] += w * h4.y;
            ga[u*4+2] += w * h4.z; ga[u*4+3] += w * h4.w;
        }
    }
    // P2: acc = bias + h@Ws (h from hb row r, Ws from LDS)
    const int j0 = q * NCOL;
    float acc[NCOL];
    {
        const float4* bv = (const float4*)(bias + j0);
        #pragma unroll
        for (int q4 = 0; q4 < NCOL / 4; ++q4) {
            const float4 b4 = bv[q4];
            acc[q4*4+0] = b4.x; acc[q4*4+1] = b4.y; acc[q4*4+2] = b4.z; acc[q4*4+3] = b4.w;
        }
    }
    const int rbase = r * 16, rsw = r & 15;
    const float* wsl = wlds + 64 * OUTW;
    for (int ic = 0; ic < 16; ++ic) {
        const float4 h4 = hb4[rbase + (ic ^ rsw)];
        const float hv[4] = {h4.x, h4.y, h4.z, h4.w};
        #pragma unroll
        for (int u = 0; u < 4; ++u) {
            const int i = ic * 4 + u;
            const float h = hv[u];
            const float* wr = wsl + i * OUTW + j0;
            #pragma unroll
            for (int q4 = 0; q4 < NCOL / 4; ++q4) {
                const float4 w4 = *(const float4*)(wr + q4 * 4);
                acc[q4*4+0] += h * w4.x; acc[q4*4+1] += h * w4.y;
                acc[q4*4+2] += h * w4.z; acc[q4*4+3] += h * w4.w;
            }
        }
    }
    __syncthreads();                          // [B1] all h reads done
    // P3: overwrite hb row r chunks with agg
    {
        #pragma unroll
        for (int u = 0; u < 4; ++u) {
            float4 v; v.x = ga[u*4+0]; v.y = ga[u*4+1]; v.z = ga[u*4+2]; v.w = ga[u*4+3];
            hb4[rbase + ((cb + u) ^ rsw)] = v;
        }
    }
    __syncthreads();                          // [B2] agg visible
    // P4: acc += agg@Wm (agg from hb row r, Wm from LDS)
    for (int ic = 0; ic < 16; ++ic) {
        const float4 a4 = hb4[rbase + (ic ^ rsw)];
        const float av[4] = {a4.x, a4.y, a4.z, a4.w};
        #pragma unroll
        for (int u = 0; u < 4; ++u) {
            const int i = ic * 4 + u;
            const float a = av[u];
            const float* wr = wlds + i * OUTW + j0;
            #pragma unroll
            for (int q4 = 0; q4 < NCOL / 4; ++q4) {
                const float4 w4 = *(const float4*)(wr + q4 * 4);
                acc[q4*4+0] += a * w4.x; acc[q4*4+1] += a * w4.y;
                acc[q4*4+2] += a * w4.z; acc[q4*4+3] += a * w4.w;
            }
        }
    }
    #pragma unroll
    for (int jj = 0; jj < NCOL; ++jj) acc[jj] = fmaxf(acc[jj], 0.f);
    __syncthreads();                          // [B3] agg reads done
    // P5: write h_next
    if (WRITE_H) {
        #pragma unroll
        for (int u = 0; u < NCOL / 4; ++u) {
            float4 v; v.x = acc[u*4+0]; v.y = acc[u*4+1]; v.z = acc[u*4+2]; v.w = acc[u*4+3];
            hb4[rbase + ((cb + u) ^ rsw)] = v;
        }
    }
    // FC: p = acc @ Wc[rows j0..j0+NCOL); quad shfl-reduce; q0 owns lgl[r] RMW
    {
        float p[16];
        #pragma unroll
        for (int k = 0; k < 16; ++k) p[k] = 0.f;
        #pragma unroll
        for (int jj = 0; jj < NCOL; ++jj) {
            const float a = acc[jj];
            const float* wr = wc + (j0 + jj) * 16;
            #pragma unroll
            for (int q4 = 0; q4 < 4; ++q4) {
                const float4 w4 = *(const float4*)(wr + q4 * 4);
                p[q4*4+0] += a * w4.x; p[q4*4+1] += a * w4.y;
                p[q4*4+2] += a * w4.z; p[q4*4+3] += a * w4.w;
            }
        }
        #pragma unroll
        for (int k = 0; k < 16; ++k) p[k] += __shfl_xor(p[k], 1);
        #pragma unroll
        for (int k = 0; k < 16; ++k) p[k] += __shfl_xor(p[k], 2);
        if (q == 0) {
            float* Lr = lgl + r * 17;
            #pragma unroll
            for (int k = 0; k < 16; ++k) Lr[k] += p[k];
        }
    }
    __syncthreads();                          // [B4] h_next visible / wlds reusable
}

__launch_bounds__(1024)
__global__ void gconv_kernel(
    const float* __restrict__ x,
    const float* __restrict__ Wm0, const float* __restrict__ Ws0, const float* __restrict__ b0,
    const float* __restrict__ Wm1, const float* __restrict__ Ws1, const float* __restrict__ b1,
    const float* __restrict__ Wm2, const float* __restrict__ Ws2, const float* __restrict__ b2,
    const float* __restrict__ wcomb, const float* __restrict__ bcomb,
    const float* __restrict__ wrec, const unsigned char* __restrict__ clrec,
    const int* __restrict__ indptr,
    float* __restrict__ out, float* __restrict__ entpart)
{
    __shared__ float4 hb4[4096];       // h/agg tile, XOR-chunk-swizzled (64 KB)
    __shared__ float  wlds[2*64*64];   // Wm,Ws staging (32 KB)
    __shared__ float  lgl[NN * 17];    // logits accumulator (17 KB)
    __shared__ float  red[16];
    const int t = threadIdx.x;
    const int bid = blockIdx.x;
    const int d = bid >> 8;
    const int b = bid & (NB - 1);
    const int r = t >> 2;          // row
    const int q = t & 3;           // channel quarter
    const int lane = t & 63;
    const int wave = t >> 6;

    // stage x -> hb (swizzled) ; zero logits
    {
        const float4* xv = (const float4*)(x + (size_t)b * NN * HID);
        #pragma unroll
        for (int it = 0; it < 4; ++it) {
            const int idx = t + it * 1024;
            const int nrow = idx >> 4, c = idx & 15;
            hb4[nrow * 16 + (c ^ (nrow & 15))] = xv[idx];
        }
        for (int i = t; i < NN * 17; i += 1024) lgl[i] = 0.f;
    }

    const float* wp = wrec + (size_t)d * NB * EPG + (size_t)b * EPG;
    const unsigned char* clp = clrec + (size_t)b * EPG;
    const int js = indptr[b * 257 + r];
    const int je = indptr[b * 257 + r + 1];

    layer_step<64, true >(t, r, q, js, je, wp, clp, Wm0 + d*HID*HID, Ws0 + d*HID*HID,
                          b0 + d*HID, wcomb,            hb4, wlds, lgl);
    layer_step<64, true >(t, r, q, js, je, wp, clp, Wm1 + d*HID*HID, Ws1 + d*HID*HID,
                          b1 + d*HID, wcomb + 64*16,    hb4, wlds, lgl);
    layer_step<16, false>(t, r, q, js, je, wp, clp, Wm2 + d*HID*KK,  Ws2 + d*HID*KK,
                          b2 + d*KK,  wcomb + 128*16,   hb4, wlds, lgl);

    // softmax + entropy: threads t<256, row = t
    float ent_local = 0.f;
    if (t < 256) {
        const int rr = t;
        float logits[KK];
        const float* Lr = lgl + rr * 17;
        #pragma unroll
        for (int k = 0; k < KK; ++k) logits[k] = Lr[k] + bcomb[k];
        float m = logits[0];
        #pragma unroll
        for (int k = 1; k < KK; ++k) m = fmaxf(m, logits[k]);
        float sum = 0.f, sv[KK];
        #pragma unroll
        for (int k = 0; k < KK; ++k) { sv[k] = expf(logits[k] - m); sum += sv[k]; }
        const float inv = 1.f / sum;
        float4* sp4 = (float4*)(out + S_OFF + ((size_t)(d * NB + b) * NN + rr) * KK);
        #pragma unroll
        for (int q4 = 0; q4 < 4; ++q4) {
            float4 v;
            const float s0 = sv[q4*4+0] * inv, s1 = sv[q4*4+1] * inv;
            const float s2 = sv[q4*4+2] * inv, s3 = sv[q4*4+3] * inv;
            v.x = s0; v.y = s1; v.z = s2; v.w = s3;
            sp4[q4] = v;
            ent_local -= s0 * logf(s0 + 1e-15f) + s1 * logf(s1 + 1e-15f)
                       + s2 * logf(s2 + 1e-15f) + s3 * logf(s3 + 1e-15f);
        }
    }
    #pragma unroll
    for (int off = 32; off; off >>= 1) ent_local += __shfl_down(ent_local, off);
    if (lane == 0) red[wave] = ent_local;
    __syncthreads();
    if (t == 0) {
        float s = 0.f;
        #pragma unroll
        for (int w = 0; w < 16; ++w) s += red[w];
        entpart[bid] = s;
    }
}

// ---------------- pool: padj = sum_r s[r] (x) G[r], G = A s ; + mod + px ----------------
#define SSTR 20
__launch_bounds__(256)
__global__ void pool_kernel(
    const float* __restrict__ x_to_pool,
    const float* __restrict__ wrec, const unsigned char* __restrict__ clrec,
    const int* __restrict__ indptr,
    const float* __restrict__ out_s, float* __restrict__ out, float* __restrict__ modpart)
{
    __shared__ float sl[NN * SSTR];       // 20 KB
    __shared__ float gl[NN * SSTR];       // 20 KB
    __shared__ float padjw[4 * 256];      // per-wave partials (deterministic merge)
    __shared__ float red[4];
    const int t = threadIdx.x;
    const int bid = blockIdx.x;
    const int d = bid >> 8;
    const int b = bid & (NB - 1);
    const int lane = t & 63;
    const int wave = t >> 6;

    {
        const float4* sp4 = (const float4*)(out_s + S_OFF + (size_t)(d * NB + b) * NN * KK);
        #pragma unroll
        for (int it = 0; it < 4; ++it) {
            const int idx = t + it * 256;
            const int nrow = idx >> 2, c = idx & 3;
            *(float4*)(sl + nrow * SSTR + c * 4) = sp4[idx];
        }
    }
    __syncthreads();

    const float* wp = wrec + (size_t)d * NB * EPG + (size_t)b * EPG;
    const unsigned char* clp = clrec + (size_t)b * EPG;
    const int js = indptr[b * 257 + t];
    const int je = indptr[b * 257 + t + 1];
    float sr[16];
    {
        #pragma unroll
        for (int c = 0; c < 4; ++c) {
            const float4 v = *(const float4*)(sl + t * SSTR + c * 4);
            sr[c*4+0] = v.x; sr[c*4+1] = v.y; sr[c*4+2] = v.z; sr[c*4+3] = v.w;
        }
    }
    float g[16];
    #pragma unroll
    for (int k = 0; k < 16; ++k) g[k] = 0.f;
    float modacc = 0.f;
    for (int j = js; j < je; ++j) {
        const int cl = clp[j];
        const float w = wp[j];
        const float* srow = sl + cl * SSTR;
        float ss = 0.f;
        #pragma unroll
        for (int c = 0; c < 4; ++c) {
            const float4 sv = *(const float4*)(srow + c * 4);
            g[c*4+0] += w * sv.x; g[c*4+1] += w * sv.y;
            g[c*4+2] += w * sv.z; g[c*4+3] += w * sv.w;
            const float d0 = sr[c*4+0] - sv.x, d1 = sr[c*4+1] - sv.y;
            const float d2 = sr[c*4+2] - sv.z, d3 = sr[c*4+3] - sv.w;
            ss += d0*d0 + d1*d1 + d2*d2 + d3*d3;
        }
        modacc += w * ss;
    }
    {
        #pragma unroll
        for (int c = 0; c < 4; ++c) {
            float4 v; v.x = g[c*4+0]; v.y = g[c*4+1]; v.z = g[c*4+2]; v.w = g[c*4+3];
            *(float4*)(gl + t * SSTR + c * 4) = v;
        }
    }
    __syncthreads();

    // padj[k][l] = sum_r s[r][k] * G[r][l]; wave w covers r in [w*64, w*64+64)
    {
        const int k = t & 15, lg = (t >> 4) & 3;
        float p0 = 0.f, p1 = 0.f, p2 = 0.f, p3 = 0.f;
        const int r0 = wave * 64;
        for (int rr = r0; rr < r0 + 64; ++rr) {
            const float sk = sl[rr * SSTR + k];
            const float4 g4 = *(const float4*)(gl + rr * SSTR + lg * 4);
            p0 += sk * g4.x; p1 += sk * g4.y; p2 += sk * g4.z; p3 += sk * g4.w;
        }
        float* pw = padjw + wave * 256 + k * 16 + lg * 4;
        pw[0] = p0; pw[1] = p1; pw[2] = p2; pw[3] = p3;
    }

    // px[k][f] = sum_n s[n][k] * xtp[n][f*3+d]
    {
        const int f = t & 63;
        const int kg = t >> 6;
        float xa0 = 0.f, xa1 = 0.f, xa2 = 0.f, xa3 = 0.f;
        const float* xp = x_to_pool + (size_t)b * NN * (64 * DIMS) + f * DIMS + d;
        #pragma unroll 4
        for (int nn2 = 0; nn2 < NN; ++nn2) {
            const float xv = xp[(size_t)nn2 * (64 * DIMS)];
            const float4 s4 = *(const float4*)(sl + nn2 * SSTR + kg * 4);
            xa0 += xv * s4.x; xa1 += xv * s4.y; xa2 += xv * s4.z; xa3 += xv * s4.w;
        }
        const float sc = 1.f / 16.f;  // K/N
        out[PX_OFF + ((size_t)((b * KK + kg * 4 + 0) * 64) + f) * DIMS + d] = xa0 * sc;
        out[PX_OFF + ((size_t)((b * KK + kg * 4 + 1) * 64) + f) * DIMS + d] = xa1 * sc;
        out[PX_OFF + ((size_t)((b * KK + kg * 4 + 2) * 64) + f) * DIMS + d] = xa2 * sc;
        out[PX_OFF + ((size_t)((b * KK + kg * 4 + 3) * 64) + f) * DIMS + d] = xa3 * sc;
    }

    #pragma unroll
    for (int off = 32; off; off >>= 1) modacc += __shfl_down(modacc, off);
    if (lane == 0) red[wave] = modacc;
    __syncthreads();   // also fences padjw
    if (t == 0) modpart[bid] = red[0] + red[1] + red[2] + red[3];

    {
        const float v = (padjw[t] + padjw[256 + t] + padjw[512 + t] + padjw[768 + t]) * (1.f / 256.f);
        out[PEA_OFF + (size_t)((b * KK + (t >> 4)) * KK + (t & 15)) * DIMS + d] = v;
    }
}

__global__ void aux_kernel(float* __restrict__ out)
{
    const int idx = blockIdx.x * 256 + threadIdx.x;
    if (idx < 2 * NTOT) {
        const int r = idx & (NTOT - 1);
        const int bb = r >> 8;
        const int j = r & 255;
        const int v = (idx < NTOT) ? (bb * KK + (j >> 4)) : (bb * KK + (j & 15));
        out[PEI_OFF + idx] = (float)v;
    } else if (idx < 2 * NTOT + NB * KK) {
        const int i = idx - 2 * NTOT;
        out[PB_OFF + i] = (float)(i >> 4);
    }
}

__global__ void loss_kernel(const float* __restrict__ entpart,
                            const float* __restrict__ modpart,
                            float* __restrict__ out)
{
    const int tid = threadIdx.x;
    float e = 0.f, m = 0.f;
    for (int i = tid; i < DIMS * NB; i += 256) { e += entpart[i]; m += modpart[i]; }
    #pragma unroll
    for (int off = 32; off; off >>= 1) { e += __shfl_down(e, off); m += __shfl_down(m, off); }
    __shared__ float er[4], mr[4];
    const int wave = tid >> 6, lane = tid & 63;
    if (lane == 0) { er[wave] = e; mr[wave] = m; }
    __syncthreads();
    if (tid == 0) {
        const float es = er[0] + er[1] + er[2] + er[3];
        const float ms = mr[0] + mr[1] + mr[2] + mr[3];
        out[LOSS_OFF] = ms / (float)NE + es / (float)(DIMS * NTOT);
    }
}

extern "C" void kernel_launch(void* const* d_in, const int* in_sizes, int n_in,
                              void* d_out, int out_size, void* d_ws, size_t ws_size,
                              hipStream_t stream)
{
    const float* x         = (const float*)d_in[0];
    const float* edge_attr = (const float*)d_in[1];
    const float* x_to_pool = (const float*)d_in[2];
    const float* Wm0 = (const float*)d_in[3];
    const float* Ws0 = (const float*)d_in[4];
    const float* b0  = (const float*)d_in[5];
    const float* Wm1 = (const float*)d_in[6];
    const float* Ws1 = (const float*)d_in[7];
    const float* b1  = (const float*)d_in[8];
    const float* Wm2 = (const float*)d_in[9];
    const float* Ws2 = (const float*)d_in[10];
    const float* b2  = (const float*)d_in[11];
    const float* fcW1= (const float*)d_in[12];
    const float* fcb1= (const float*)d_in[13];
    const float* fcW2= (const float*)d_in[14];
    const float* fcb2= (const float*)d_in[15];
    const int* edge_index = (const int*)d_in[16];
    float* out = (float*)d_out;
    char* ws = (char*)d_ws;
    float*         wrec  = (float*)(ws + WREC_WS);
    unsigned char* clrec = (unsigned char*)(ws + CLREC_WS);
    int*           iptr  = (int*)(ws + IPTR_WS);
    float*         entpart = (float*)(ws + ENT_WS);
    float*         modpart = (float*)(ws + MOD_WS);
    float*         wc    = (float*)(ws + WC_WS);
    float*         bc    = (float*)(ws + BC_WS);

    csr_build<<<dim3(NB), dim3(256), 0, stream>>>(edge_index, edge_attr, wrec, clrec, iptr);
    fc_combine<<<dim3(1), dim3(256), 0, stream>>>(fcW1, fcb1, fcW2, fcb2, wc, bc);
    gconv_kernel<<<dim3(DIMS * NB), dim3(1024), 0, stream>>>(
        x, Wm0, Ws0, b0, Wm1, Ws1, b1, Wm2, Ws2, b2,
        wc, bc, wrec, clrec, iptr, out, entpart);
    pool_kernel<<<dim3(DIMS * NB), dim3(256), 0, stream>>>(
        x_to_pool, wrec, clrec, iptr, out, out, modpart);
    aux_kernel<<<dim3((2 * NTOT + NB * KK + 255) / 256), dim3(256), 0, stream>>>(out);
    loss_kernel<<<dim3(1), dim3(256), 0, stream>>>(entpart, modpart, out);
}

// Round 8
// 624.628 us; speedup vs baseline: 3.3833x; 1.6827x over previous
//
#include <hip/hip_runtime.h>

#define DIMS 3
#define NB 256
#define NN 256
#define KK 16
#define HID 64
#define EPG 8192
#define NTOT (NB*NN)
#define NE (NB*EPG)

// d_out layout (flat concat of reference outputs, all as float)
#define PX_OFF   0          // (B*K, F, DIMS)           = 786432
#define PEI_OFF  786432     // (2, B*K*K)               = 131072
#define PEA_OFF  917504     // (B*K*K, DIMS)            = 196608
#define PB_OFF   1114112    // (B*K,)                   = 4096
#define LOSS_OFF 1118208    // scalar
#define S_OFF    1118209    // (DIMS, B, N, K)          = 3145728

// d_ws layout (bytes) — total ~27.5 MB
#define WREC_WS  0                 // float[3][NB*EPG] per-d edge weight (CSR order) = 24 MB
#define CLREC_WS 25165824          // uchar[NB*EPG] col-local index
#define IPTR_WS  27262976          // int[NB*257]
#define ENT_WS   27526144          // float[768]
#define MOD_WS   27529216          // float[768]
#define WC_WS    27532288          // float[144*16]  (fcW1 @ fcW2)
#define BC_WS    27541504          // float[16]      (fcb1 @ fcW2 + fcb2)

// ---------------- combined FC weights: Wc = fcW1@fcW2, bc = fcb1@fcW2+fcb2 ----------------
__global__ void fc_combine(const float* __restrict__ fcW1, const float* __restrict__ fcb1,
                           const float* __restrict__ fcW2, const float* __restrict__ fcb2,
                           float* __restrict__ wc, float* __restrict__ bc)
{
    const int t = threadIdx.x;
    for (int idx = t; idx < 144 * 16; idx += 256) {
        const int i = idx >> 4, k = idx & 15;
        float s = 0.f;
        for (int q = 0; q < 50; ++q) s += fcW1[i * 50 + q] * fcW2[q * 16 + k];
        wc[idx] = s;
    }
    if (t < 16) {
        float s = fcb2[t];
        for (int q = 0; q < 50; ++q) s += fcb1[q] * fcW2[q * 16 + t];
        bc[t] = s;
    }
}

// ------- CSR build: parallel deterministic counting sort (strided chunks) -------
// Thread t<128 owns edges {t + 128*j}. h[r][t] = count of row r in chunk t (u8).
// po[r][t] = start[r] + prefix over chunks (u16). Placement: dest = po[r][t]++
// (single writer per column, no atomics) -> deterministic run-to-run.
#define HSTR 132   // u8 row stride: bank = (r*33 + t/4)%32 -> spread
#define PSTR 129   // u16 row stride: bank varies with t in B2 row walk
__launch_bounds__(256)
__global__ void csr_build(const int* __restrict__ edge_index,
                          const float* __restrict__ edge_attr,
                          float* __restrict__ wrec, unsigned char* __restrict__ clrec,
                          int* __restrict__ indptr)
{
    __shared__ unsigned char  h[256 * HSTR];    // 33.8 KB
    __shared__ unsigned short po[256 * PSTR];   // 66.0 KB
    __shared__ int sc[256];
    const int b = blockIdx.x;
    const int t = threadIdx.x;
    const int* rowp = edge_index + (size_t)b * EPG;
    const int* colp = edge_index + (size_t)NB * EPG + (size_t)b * EPG;

    // zero h
    for (int i = t; i < 256 * HSTR / 4; i += 256) ((unsigned int*)h)[i] = 0u;
    __syncthreads();

    // phase A: chunk histograms (coalesced global row reads)
    if (t < 128) {
        #pragma unroll 4
        for (int j = 0; j < 64; ++j) {
            const int r = rowp[t + 128 * j] & (NN - 1);
            h[r * HSTR + t]++;
        }
    }
    __syncthreads();

    // phase B1: row totals (row = t); pad bytes are zero
    int tot;
    {
        int s = 0;
        const unsigned int* hr = (const unsigned int*)(h + t * HSTR);
        #pragma unroll
        for (int c4 = 0; c4 < HSTR / 4; ++c4) {
            const unsigned int v = hr[c4];
            s += (v & 255) + ((v >> 8) & 255) + ((v >> 16) & 255) + (v >> 24);
        }
        tot = s;
        sc[t] = s;
    }
    __syncthreads();
    // inclusive scan
    for (int ofs = 1; ofs < 256; ofs <<= 1) {
        int v = (t >= ofs) ? sc[t - ofs] : 0;
        __syncthreads();
        sc[t] += v;
        __syncthreads();
    }
    const int start = sc[t] - tot;
    indptr[b * 257 + t] = start;
    if (t == 255) indptr[b * 257 + 256] = EPG;

    // phase B2: running prefix po[t][c] over chunks
    {
        int run = start;
        #pragma unroll 4
        for (int c = 0; c < 128; ++c) {
            po[t * PSTR + c] = (unsigned short)run;
            run += h[t * HSTR + c];
        }
    }
    __syncthreads();

    // phase C: place edges (chunk order j ascending; deterministic)
    if (t < 128) {
        const float* eap = edge_attr + (size_t)b * EPG * 3;
        float* w0 = wrec + (size_t)b * EPG;
        float* w1 = wrec + (size_t)NB * EPG + (size_t)b * EPG;
        float* w2 = wrec + 2 * (size_t)NB * EPG + (size_t)b * EPG;
        unsigned char* cdst = clrec + (size_t)b * EPG;
        #pragma unroll 2
        for (int j = 0; j < 64; ++j) {
            const int e = t + 128 * j;
            const int r = rowp[e] & (NN - 1);
            const int cl = colp[e] & (NN - 1);
            const int dest = po[r * PSTR + t]++;
            w0[dest] = eap[e * 3 + 0];
            w1[dest] = eap[e * 3 + 1];
            w2[dest] = eap[e * 3 + 2];
            cdst[dest] = (unsigned char)cl;
        }
    }
}

// -------- gconv: thread = (row r, quarter q) = ((t>>2), (t&3)); no persistent per-thread
// arrays (FC logits accumulate in LDS via single-owner RMW). One h buffer (agg overwrites h
// mid-layer). Weights staged in LDS. Peak live regs ~50 -> no scratch at any VGPR budget. --------
template<int OUTW, bool WRITE_H>
__device__ __forceinline__ void layer_step(
    int t, int r, int q, int js, int je,
    const float* __restrict__ wp, const unsigned char* __restrict__ clp,
    const float* __restrict__ Wm, const float* __restrict__ Ws,
    const float* __restrict__ bias, const float* __restrict__ wc, // wc + layer_row_off*16
    float4* hb4, float* wlds, float* lgl)
{
    constexpr int NCOL = OUTW / 4;            // dense outputs per thread (16 or 4)
    constexpr int NF4  = 64 * OUTW / 4;       // float4 count of one weight matrix
    // stage Wm,Ws -> LDS (prev layer's wlds reads ended before its last barrier)
    {
        const float4* wmv = (const float4*)Wm;
        const float4* wsv = (const float4*)Ws;
        float4* dm = (float4*)wlds;
        float4* ds = dm + NF4;
        for (int i = t; i < NF4; i += 1024) dm[i] = wmv[i];
        for (int i = t; i < NF4; i += 1024) ds[i] = wsv[i];
    }
    __syncthreads();                          // [B0] h stable + weights visible
    // P1: gather ga[16] (channels q*16..+16) over this row's CSR edges
    float ga[16];
    #pragma unroll
    for (int u = 0; u < 16; ++u) ga[u] = 0.f;
    const int cb = q * 4;
    for (int j = js; j < je; ++j) {
        const int cl = clp[j];
        const float w = wp[j];
        const int base = cl * 16, sw = cl & 15;
        #pragma unroll
        for (int u = 0; u < 4; ++u) {
            const float4 h4 = hb4[base + ((cb + u) ^ sw)];
            ga[u*4+0] += w * h4.x; ga[u*4+1] += w * h4.y;
            ga[u*4+2] += w * h4.z; ga[u*4+3] += w * h4.w;
        }
    }
    // P2: acc = bias + h@Ws (h from hb row r, Ws from LDS)
    const int j0 = q * NCOL;
    float acc[NCOL];
    {
        const float4* bv = (const float4*)(bias + j0);
        #pragma unroll
        for (int q4 = 0; q4 < NCOL / 4; ++q4) {
            const float4 b4 = bv[q4];
            acc[q4*4+0] = b4.x; acc[q4*4+1] = b4.y; acc[q4*4+2] = b4.z; acc[q4*4+3] = b4.w;
        }
    }
    const int rbase = r * 16, rsw = r & 15;
    const float* wsl = wlds + 64 * OUTW;
    for (int ic = 0; ic < 16; ++ic) {
        const float4 h4 = hb4[rbase + (ic ^ rsw)];
        const float hv[4] = {h4.x, h4.y, h4.z, h4.w};
        #pragma unroll
        for (int u = 0; u < 4; ++u) {
            const int i = ic * 4 + u;
            const float h = hv[u];
            const float* wr = wsl + i * OUTW + j0;
            #pragma unroll
            for (int q4 = 0; q4 < NCOL / 4; ++q4) {
                const float4 w4 = *(const float4*)(wr + q4 * 4);
                acc[q4*4+0] += h * w4.x; acc[q4*4+1] += h * w4.y;
                acc[q4*4+2] += h * w4.z; acc[q4*4+3] += h * w4.w;
            }
        }
    }
    __syncthreads();                          // [B1] all h reads done
    // P3: overwrite hb row r chunks with agg
    {
        #pragma unroll
        for (int u = 0; u < 4; ++u) {
            float4 v; v.x = ga[u*4+0]; v.y = ga[u*4+1]; v.z = ga[u*4+2]; v.w = ga[u*4+3];
            hb4[rbase + ((cb + u) ^ rsw)] = v;
        }
    }
    __syncthreads();                          // [B2] agg visible
    // P4: acc += agg@Wm (agg from hb row r, Wm from LDS)
    for (int ic = 0; ic < 16; ++ic) {
        const float4 a4 = hb4[rbase + (ic ^ rsw)];
        const float av[4] = {a4.x, a4.y, a4.z, a4.w};
        #pragma unroll
        for (int u = 0; u < 4; ++u) {
            const int i = ic * 4 + u;
            const float a = av[u];
            const float* wr = wlds + i * OUTW + j0;
            #pragma unroll
            for (int q4 = 0; q4 < NCOL / 4; ++q4) {
                const float4 w4 = *(const float4*)(wr + q4 * 4);
                acc[q4*4+0] += a * w4.x; acc[q4*4+1] += a * w4.y;
                acc[q4*4+2] += a * w4.z; acc[q4*4+3] += a * w4.w;
            }
        }
    }
    #pragma unroll
    for (int jj = 0; jj < NCOL; ++jj) acc[jj] = fmaxf(acc[jj], 0.f);
    __syncthreads();                          // [B3] agg reads done
    // P5: write h_next
    if (WRITE_H) {
        #pragma unroll
        for (int u = 0; u < NCOL / 4; ++u) {
            float4 v; v.x = acc[u*4+0]; v.y = acc[u*4+1]; v.z = acc[u*4+2]; v.w = acc[u*4+3];
            hb4[rbase + ((cb + u) ^ rsw)] = v;
        }
    }
    // FC: p = acc @ Wc[rows j0..j0+NCOL); quad shfl-reduce; q0 owns lgl[r] RMW
    {
        float p[16];
        #pragma unroll
        for (int k = 0; k < 16; ++k) p[k] = 0.f;
        #pragma unroll
        for (int jj = 0; jj < NCOL; ++jj) {
            const float a = acc[jj];
            const float* wr = wc + (j0 + jj) * 16;
            #pragma unroll
            for (int q4 = 0; q4 < 4; ++q4) {
                const float4 w4 = *(const float4*)(wr + q4 * 4);
                p[q4*4+0] += a * w4.x; p[q4*4+1] += a * w4.y;
                p[q4*4+2] += a * w4.z; p[q4*4+3] += a * w4.w;
            }
        }
        #pragma unroll
        for (int k = 0; k < 16; ++k) p[k] += __shfl_xor(p[k], 1);
        #pragma unroll
        for (int k = 0; k < 16; ++k) p[k] += __shfl_xor(p[k], 2);
        if (q == 0) {
            float* Lr = lgl + r * 17;
            #pragma unroll
            for (int k = 0; k < 16; ++k) Lr[k] += p[k];
        }
    }
    __syncthreads();                          // [B4] h_next visible / wlds reusable
}

__launch_bounds__(1024)
__global__ void gconv_kernel(
    const float* __restrict__ x,
    const float* __restrict__ Wm0, const float* __restrict__ Ws0, const float* __restrict__ b0,
    const float* __restrict__ Wm1, const float* __restrict__ Ws1, const float* __restrict__ b1,
    const float* __restrict__ Wm2, const float* __restrict__ Ws2, const float* __restrict__ b2,
    const float* __restrict__ wcomb, const float* __restrict__ bcomb,
    const float* __restrict__ wrec, const unsigned char* __restrict__ clrec,
    const int* __restrict__ indptr,
    float* __restrict__ out, float* __restrict__ entpart)
{
    __shared__ float4 hb4[4096];       // h/agg tile, XOR-chunk-swizzled (64 KB)
    __shared__ float  wlds[2*64*64];   // Wm,Ws staging (32 KB)
    __shared__ float  lgl[NN * 17];    // logits accumulator (17 KB)
    __shared__ float  red[16];
    const int t = threadIdx.x;
    const int bid = blockIdx.x;
    const int d = bid >> 8;
    const int b = bid & (NB - 1);
    const int r = t >> 2;          // row
    const int q = t & 3;           // channel quarter
    const int lane = t & 63;
    const int wave = t >> 6;

    // stage x -> hb (swizzled) ; zero logits
    {
        const float4* xv = (const float4*)(x + (size_t)b * NN * HID);
        #pragma unroll
        for (int it = 0; it < 4; ++it) {
            const int idx = t + it * 1024;
            const int nrow = idx >> 4, c = idx & 15;
            hb4[nrow * 16 + (c ^ (nrow & 15))] = xv[idx];
        }
        for (int i = t; i < NN * 17; i += 1024) lgl[i] = 0.f;
    }

    const float* wp = wrec + (size_t)d * NB * EPG + (size_t)b * EPG;
    const unsigned char* clp = clrec + (size_t)b * EPG;
    const int js = indptr[b * 257 + r];
    const int je = indptr[b * 257 + r + 1];

    layer_step<64, true >(t, r, q, js, je, wp, clp, Wm0 + d*HID*HID, Ws0 + d*HID*HID,
                          b0 + d*HID, wcomb,            hb4, wlds, lgl);
    layer_step<64, true >(t, r, q, js, je, wp, clp, Wm1 + d*HID*HID, Ws1 + d*HID*HID,
                          b1 + d*HID, wcomb + 64*16,    hb4, wlds, lgl);
    layer_step<16, false>(t, r, q, js, je, wp, clp, Wm2 + d*HID*KK,  Ws2 + d*HID*KK,
                          b2 + d*KK,  wcomb + 128*16,   hb4, wlds, lgl);

    // softmax + entropy: threads t<256, row = t
    float ent_local = 0.f;
    if (t < 256) {
        const int rr = t;
        float logits[KK];
        const float* Lr = lgl + rr * 17;
        #pragma unroll
        for (int k = 0; k < KK; ++k) logits[k] = Lr[k] + bcomb[k];
        float m = logits[0];
        #pragma unroll
        for (int k = 1; k < KK; ++k) m = fmaxf(m, logits[k]);
        float sum = 0.f, sv[KK];
        #pragma unroll
        for (int k = 0; k < KK; ++k) { sv[k] = expf(logits[k] - m); sum += sv[k]; }
        const float inv = 1.f / sum;
        float4* sp4 = (float4*)(out + S_OFF + ((size_t)(d * NB + b) * NN + rr) * KK);
        #pragma unroll
        for (int q4 = 0; q4 < 4; ++q4) {
            float4 v;
            const float s0 = sv[q4*4+0] * inv, s1 = sv[q4*4+1] * inv;
            const float s2 = sv[q4*4+2] * inv, s3 = sv[q4*4+3] * inv;
            v.x = s0; v.y = s1; v.z = s2; v.w = s3;
            sp4[q4] = v;
            ent_local -= s0 * logf(s0 + 1e-15f) + s1 * logf(s1 + 1e-15f)
                       + s2 * logf(s2 + 1e-15f) + s3 * logf(s3 + 1e-15f);
        }
    }
    #pragma unroll
    for (int off = 32; off; off >>= 1) ent_local += __shfl_down(ent_local, off);
    if (lane == 0) red[wave] = ent_local;
    __syncthreads();
    if (t == 0) {
        float s = 0.f;
        #pragma unroll
        for (int w = 0; w < 16; ++w) s += red[w];
        entpart[bid] = s;
    }
}

// ---------------- pool: padj = sum_r s[r] (x) G[r], G = A s ; + mod + px ----------------
#define SSTR 20
__launch_bounds__(256)
__global__ void pool_kernel(
    const float* __restrict__ x_to_pool,
    const float* __restrict__ wrec, const unsigned char* __restrict__ clrec,
    const int* __restrict__ indptr,
    const float* __restrict__ out_s, float* __restrict__ out, float* __restrict__ modpart)
{
    __shared__ float sl[NN * SSTR];       // 20 KB
    __shared__ float gl[NN * SSTR];       // 20 KB
    __shared__ float padjw[4 * 256];      // per-wave partials (deterministic merge)
    __shared__ float red[4];
    const int t = threadIdx.x;
    const int bid = blockIdx.x;
    const int d = bid >> 8;
    const int b = bid & (NB - 1);
    const int lane = t & 63;
    const int wave = t >> 6;

    {
        const float4* sp4 = (const float4*)(out_s + S_OFF + (size_t)(d * NB + b) * NN * KK);
        #pragma unroll
        for (int it = 0; it < 4; ++it) {
            const int idx = t + it * 256;
            const int nrow = idx >> 2, c = idx & 3;
            *(float4*)(sl + nrow * SSTR + c * 4) = sp4[idx];
        }
    }
    __syncthreads();

    const float* wp = wrec + (size_t)d * NB * EPG + (size_t)b * EPG;
    const unsigned char* clp = clrec + (size_t)b * EPG;
    const int js = indptr[b * 257 + t];
    const int je = indptr[b * 257 + t + 1];
    float sr[16];
    {
        #pragma unroll
        for (int c = 0; c < 4; ++c) {
            const float4 v = *(const float4*)(sl + t * SSTR + c * 4);
            sr[c*4+0] = v.x; sr[c*4+1] = v.y; sr[c*4+2] = v.z; sr[c*4+3] = v.w;
        }
    }
    float g[16];
    #pragma unroll
    for (int k = 0; k < 16; ++k) g[k] = 0.f;
    float modacc = 0.f;
    for (int j = js; j < je; ++j) {
        const int cl = clp[j];
        const float w = wp[j];
        const float* srow = sl + cl * SSTR;
        float ss = 0.f;
        #pragma unroll
        for (int c = 0; c < 4; ++c) {
            const float4 sv = *(const float4*)(srow + c * 4);
            g[c*4+0] += w * sv.x; g[c*4+1] += w * sv.y;
            g[c*4+2] += w * sv.z; g[c*4+3] += w * sv.w;
            const float d0 = sr[c*4+0] - sv.x, d1 = sr[c*4+1] - sv.y;
            const float d2 = sr[c*4+2] - sv.z, d3 = sr[c*4+3] - sv.w;
            ss += d0*d0 + d1*d1 + d2*d2 + d3*d3;
        }
        modacc += w * ss;
    }
    {
        #pragma unroll
        for (int c = 0; c < 4; ++c) {
            float4 v; v.x = g[c*4+0]; v.y = g[c*4+1]; v.z = g[c*4+2]; v.w = g[c*4+3];
            *(float4*)(gl + t * SSTR + c * 4) = v;
        }
    }
    __syncthreads();

    // padj[k][l] = sum_r s[r][k] * G[r][l]; wave w covers r in [w*64, w*64+64)
    {
        const int k = t & 15, lg = (t >> 4) & 3;
        float p0 = 0.f, p1 = 0.f, p2 = 0.f, p3 = 0.f;
        const int r0 = wave * 64;
        for (int rr = r0; rr < r0 + 64; ++rr) {
            const float sk = sl[rr * SSTR + k];
            const float4 g4 = *(const float4*)(gl + rr * SSTR + lg * 4);
            p0 += sk * g4.x; p1 += sk * g4.y; p2 += sk * g4.z; p3 += sk * g4.w;
        }
        float* pw = padjw + wave * 256 + k * 16 + lg * 4;
        pw[0] = p0; pw[1] = p1; pw[2] = p2; pw[3] = p3;
    }

    // px[k][f] = sum_n s[n][k] * xtp[n][f*3+d]
    {
        const int f = t & 63;
        const int kg = t >> 6;
        float xa0 = 0.f, xa1 = 0.f, xa2 = 0.f, xa3 = 0.f;
        const float* xp = x_to_pool + (size_t)b * NN * (64 * DIMS) + f * DIMS + d;
        #pragma unroll 4
        for (int nn2 = 0; nn2 < NN; ++nn2) {
            const float xv = xp[(size_t)nn2 * (64 * DIMS)];
            const float4 s4 = *(const float4*)(sl + nn2 * SSTR + kg * 4);
            xa0 += xv * s4.x; xa1 += xv * s4.y; xa2 += xv * s4.z; xa3 += xv * s4.w;
        }
        const float sc = 1.f / 16.f;  // K/N
        out[PX_OFF + ((size_t)((b * KK + kg * 4 + 0) * 64) + f) * DIMS + d] = xa0 * sc;
        out[PX_OFF + ((size_t)((b * KK + kg * 4 + 1) * 64) + f) * DIMS + d] = xa1 * sc;
        out[PX_OFF + ((size_t)((b * KK + kg * 4 + 2) * 64) + f) * DIMS + d] = xa2 * sc;
        out[PX_OFF + ((size_t)((b * KK + kg * 4 + 3) * 64) + f) * DIMS + d] = xa3 * sc;
    }

    #pragma unroll
    for (int off = 32; off; off >>= 1) modacc += __shfl_down(modacc, off);
    if (lane == 0) red[wave] = modacc;
    __syncthreads();   // also fences padjw
    if (t == 0) modpart[bid] = red[0] + red[1] + red[2] + red[3];

    {
        const float v = (padjw[t] + padjw[256 + t] + padjw[512 + t] + padjw[768 + t]) * (1.f / 256.f);
        out[PEA_OFF + (size_t)((b * KK + (t >> 4)) * KK + (t & 15)) * DIMS + d] = v;
    }
}

__global__ void aux_kernel(float* __restrict__ out)
{
    const int idx = blockIdx.x * 256 + threadIdx.x;
    if (idx < 2 * NTOT) {
        const int r = idx & (NTOT - 1);
        const int bb = r >> 8;
        const int j = r & 255;
        const int v = (idx < NTOT) ? (bb * KK + (j >> 4)) : (bb * KK + (j & 15));
        out[PEI_OFF + idx] = (float)v;
    } else if (idx < 2 * NTOT + NB * KK) {
        const int i = idx - 2 * NTOT;
        out[PB_OFF + i] = (float)(i >> 4);
    }
}

__global__ void loss_kernel(const float* __restrict__ entpart,
                            const float* __restrict__ modpart,
                            float* __restrict__ out)
{
    const int tid = threadIdx.x;
    float e = 0.f, m = 0.f;
    for (int i = tid; i < DIMS * NB; i += 256) { e += entpart[i]; m += modpart[i]; }
    #pragma unroll
    for (int off = 32; off; off >>= 1) { e += __shfl_down(e, off); m += __shfl_down(m, off); }
    __shared__ float er[4], mr[4];
    const int wave = tid >> 6, lane = tid & 63;
    if (lane == 0) { er[wave] = e; mr[wave] = m; }
    __syncthreads();
    if (tid == 0) {
        const float es = er[0] + er[1] + er[2] + er[3];
        const float ms = mr[0] + mr[1] + mr[2] + mr[3];
        out[LOSS_OFF] = ms / (float)NE + es / (float)(DIMS * NTOT);
    }
}

extern "C" void kernel_launch(void* const* d_in, const int* in_sizes, int n_in,
                              void* d_out, int out_size, void* d_ws, size_t ws_size,
                              hipStream_t stream)
{
    const float* x         = (const float*)d_in[0];
    const float* edge_attr = (const float*)d_in[1];
    const float* x_to_pool = (const float*)d_in[2];
    const float* Wm0 = (const float*)d_in[3];
    const float* Ws0 = (const float*)d_in[4];
    const float* b0  = (const float*)d_in[5];
    const float* Wm1 = (const float*)d_in[6];
    const float* Ws1 = (const float*)d_in[7];
    const float* b1  = (const float*)d_in[8];
    const float* Wm2 = (const float*)d_in[9];
    const float* Ws2 = (const float*)d_in[10];
    const float* b2  = (const float*)d_in[11];
    const float* fcW1= (const float*)d_in[12];
    const float* fcb1= (const float*)d_in[13];
    const float* fcW2= (const float*)d_in[14];
    const float* fcb2= (const float*)d_in[15];
    const int* edge_index = (const int*)d_in[16];
    float* out = (float*)d_out;
    char* ws = (char*)d_ws;
    float*         wrec  = (float*)(ws + WREC_WS);
    unsigned char* clrec = (unsigned char*)(ws + CLREC_WS);
    int*           iptr  = (int*)(ws + IPTR_WS);
    float*         entpart = (float*)(ws + ENT_WS);
    float*         modpart = (float*)(ws + MOD_WS);
    float*         wc    = (float*)(ws + WC_WS);
    float*         bc    = (float*)(ws + BC_WS);

    csr_build<<<dim3(NB), dim3(256), 0, stream>>>(edge_index, edge_attr, wrec, clrec, iptr);
    fc_combine<<<dim3(1), dim3(256), 0, stream>>>(fcW1, fcb1, fcW2, fcb2, wc, bc);
    gconv_kernel<<<dim3(DIMS * NB), dim3(1024), 0, stream>>>(
        x, Wm0, Ws0, b0, Wm1, Ws1, b1, Wm2, Ws2, b2,
        wc, bc, wrec, clrec, iptr, out, entpart);
    pool_kernel<<<dim3(DIMS * NB), dim3(256), 0, stream>>>(
        x_to_pool, wrec, clrec, iptr, out, out, modpart);
    aux_kernel<<<dim3((2 * NTOT + NB * KK + 255) / 256), dim3(256), 0, stream>>>(out);
    loss_kernel<<<dim3(1), dim3(256), 0, stream>>>(entpart, modpart, out);
}